// Round 1
// baseline (1715.762 us; speedup 1.0000x reference)
//
#include <hip/hip_runtime.h>
#include <math.h>

// Problem constants
constexpr int Bn = 8, Cn = 128, Ln = 4096;
constexpr int DMn = 32, DIn = 64, DSn = 64;
constexpr int XCH = 192;          // DI + 2*DS conv channels
constexpr int NJ = 257;           // in_proj width: DI + (DI+2DS) + NH
constexpr int Qc = 64, NCHUNK = 64;

// Workspace layout (float offsets). Lifetime-aliased:
//  [0 .. 8388608): o1@0, o2@4194304  -> later xbc@0 (6.29M), T@6291456 (2.10M), o3@0
constexpr size_t OFF_O1   = 0;
constexpr size_t OFF_O2   = 4194304;
constexpr size_t OFF_XBC  = 0;
constexpr size_t OFF_T    = 6291456;
constexpr size_t OFF_O3   = 0;
constexpr size_t OFF_S    = 8388608;   // 1048576
constexpr size_t OFF_Z    = 9437184;   // 2097152
constexpr size_t OFF_XBCA = 11534336;  // 6291456
constexpr size_t OFF_DTS  = 17825792;  // 32768 (raw dt, then softplus'd in place)
constexpr size_t OFF_LDA  = 17858560;  // 32768
constexpr size_t OFF_CUM  = 17891328;  // 32768
constexpr size_t OFF_SPREV= 17924096;  // 2097152
constexpr size_t OFF_YRAW = 20021248;  // 2097152
constexpr size_t OFF_S2   = 22118400;  // 1048576
constexpr size_t OFF_BN   = 23166976;  // 256
// total 23167232 floats = 92.7 MB

__device__ __forceinline__ float siluf(float v) { return v / (1.0f + expf(-v)); }

// K1: o1[b,o,l] = sum_i x[b,i,l]*w[i,o] + bias[o]
__global__ void k_lin1(const float* __restrict__ x, const float* __restrict__ w,
                       const float* __restrict__ bias, float* __restrict__ o1) {
  __shared__ float xt[128][64];
  int b = blockIdx.y, l0 = blockIdx.x * 64;
  int tid = threadIdx.x, lane = tid & 63, grp = tid >> 6;
  for (int i = grp; i < 128; i += 4)
    xt[i][lane] = x[((long)b * 128 + i) * 4096 + l0 + lane];
  __syncthreads();
  int ob = grp * 32;
  float acc[32];
#pragma unroll
  for (int j = 0; j < 32; ++j) acc[j] = bias[ob + j];
  for (int i = 0; i < 128; ++i) {
    float v = xt[i][lane];
#pragma unroll
    for (int j = 0; j < 32; ++j) acc[j] += v * w[i * 128 + ob + j];
  }
#pragma unroll
  for (int j = 0; j < 32; ++j)
    o1[((long)b * 128 + ob + j) * 4096 + l0 + lane] = acc[j];
}

// K2: depthwise 3x3 SAME + bias + silu
__global__ void k_dw(const float* __restrict__ o1, const float* __restrict__ w,
                     const float* __restrict__ bias, float* __restrict__ o2) {
  int idx = blockIdx.x * 256 + threadIdx.x;
  if (idx >= Bn * Cn * Ln) return;
  int l = idx & 4095, c = (idx >> 12) & 127, b = idx >> 19;
  int h = l >> 6, wq = l & 63;
  float acc = bias[c];
  const float* wp = w + c * 9;
  const float* base = o1 + ((long)b * 128 + c) * 4096;
#pragma unroll
  for (int dh = -1; dh <= 1; ++dh)
#pragma unroll
    for (int dw_ = -1; dw_ <= 1; ++dw_) {
      int hh = h + dh, ww = wq + dw_;
      if (hh >= 0 && hh < 64 && ww >= 0 && ww < 64)
        acc += base[hh * 64 + ww] * wp[(dh + 1) * 3 + (dw_ + 1)];
    }
  o2[idx] = siluf(acc);
}

// K3: s[b,l,d] = sum_c o2[b,c,l]*w[c,d]   (d in 0..31)
__global__ void k_fcin(const float* __restrict__ o2, const float* __restrict__ w,
                       float* __restrict__ s) {
  __shared__ float t[128][64];
  int b = blockIdx.y, l0 = blockIdx.x * 64;
  int tid = threadIdx.x, lane = tid & 63, grp = tid >> 6;
  for (int c = grp; c < 128; c += 4)
    t[c][lane] = o2[((long)b * 128 + c) * 4096 + l0 + lane];
  __syncthreads();
  int db = grp * 8;
  float acc[8] = {};
  for (int c = 0; c < 128; ++c) {
    float v = t[c][lane];
#pragma unroll
    for (int j = 0; j < 8; ++j) acc[j] += v * w[c * 32 + db + j];
  }
#pragma unroll
  for (int j = 0; j < 8; ++j)
    s[((long)b * 4096 + l0 + lane) * 32 + db + j] = acc[j];
}

// K4: in_proj. For dir=1 read flipped sequence. Writes z (64), xbc (192), dtraw (1).
__global__ void k_inproj(const float* __restrict__ s, const float* __restrict__ Win,
                         float* __restrict__ z, float* __restrict__ xbc,
                         float* __restrict__ dtraw, int dir) {
  __shared__ float st[64][33];
  int b = blockIdx.y, l0 = blockIdx.x * 64;
  int tid = threadIdx.x, lane = tid & 63, grp = tid >> 6;
  for (int i = tid; i < 64 * 32; i += 256) {
    int l = i >> 5, k2 = i & 31;
    int lsrc = dir ? (4095 - (l0 + l)) : (l0 + l);
    st[l][k2] = s[((long)b * 4096 + lsrc) * 32 + k2];
  }
  __syncthreads();
  float sr[32];
#pragma unroll
  for (int k2 = 0; k2 < 32; ++k2) sr[k2] = st[lane][k2];
  long rowo = (long)b * 4096 + l0 + lane;
  const float* W = Win + (long)dir * DMn * NJ;
  int jbase = grp * 64;
  for (int jj = 0; jj < 64; ++jj) {
    int j = jbase + jj;
    float a = 0.f;
#pragma unroll
    for (int k2 = 0; k2 < 32; ++k2) a += sr[k2] * W[k2 * NJ + j];
    if (j < 64) z[rowo * 64 + j] = a;
    else xbc[rowo * 192 + (j - 64)] = a;
  }
  if (grp == 0) {
    float a = 0.f;
#pragma unroll
    for (int k2 = 0; k2 < 32; ++k2) a += sr[k2] * W[k2 * NJ + 256];
    dtraw[rowo] = a;
  }
}

// K5: causal depthwise conv1d (kernel 4) + bias + silu over 192 channels
__global__ void k_conv1d(const float* __restrict__ xbc, const float* __restrict__ w,
                         const float* __restrict__ bias, float* __restrict__ xbca, int dir) {
  long idx = (long)blockIdx.x * 256 + threadIdx.x;
  if (idx >= (long)Bn * Ln * 192) return;
  int c = (int)(idx % 192);
  long bl = idx / 192;
  int l = (int)(bl & 4095);
  const float* wp = w + dir * 768 + c * 4;
  float acc = bias[dir * 192 + c];
#pragma unroll
  for (int j = 0; j < 4; ++j) {
    int ls = l - 3 + j;
    if (ls >= 0) acc += xbc[(bl - (long)(3 - j)) * 192 + c] * wp[j];
  }
  xbca[idx] = siluf(acc);
}

// K5d: dt softplus + log-decay
__global__ void k_dt(float* __restrict__ dts, float* __restrict__ lda,
                     const float* __restrict__ dt_bias, const float* __restrict__ A_log, int dir) {
  int idx = blockIdx.x * 256 + threadIdx.x;
  if (idx >= Bn * Ln) return;
  float v = dts[idx] + dt_bias[dir];
  float sp = (v > 20.f) ? v : log1pf(expf(v));
  dts[idx] = sp;
  lda[idx] = -expf(A_log[dir]) * sp;
}

// K5b: chunk-local cumulative log-decay
__global__ void k_cum(const float* __restrict__ lda, float* __restrict__ cum) {
  int b = blockIdx.x, k = threadIdx.x;  // <<<8,64>>>
  const float* p = lda + b * 4096 + k * 64;
  float* q = cum + b * 4096 + k * 64;
  float c = 0.f;
  for (int t = 0; t < 64; ++t) { c += p[t]; q[t] = c; }
}

// K6: chunk summary T[b,k,p,n] = sum_s exp(cl_end-cl_s)*dt_s*xs_s[p]*B_s[n]
__global__ void k_chunkT(const float* __restrict__ xbca, const float* __restrict__ dts,
                         const float* __restrict__ cum, float* __restrict__ T) {
  __shared__ float Bs[64][64], Xs[64][64];
  __shared__ float f[64];
  int bk = blockIdx.x, b = bk >> 6, k = bk & 63;
  int tid = threadIdx.x, lane = tid & 63, grp = tid >> 6;
  long base = (long)b * 4096 + (long)k * 64;
  for (int r = grp; r < 64; r += 4) {
    Xs[r][lane] = xbca[(base + r) * 192 + lane];
    Bs[r][lane] = xbca[(base + r) * 192 + 64 + lane];
  }
  if (tid < 64) {
    float clend = cum[base + 63];
    f[tid] = expf(clend - cum[base + tid]) * dts[base + tid];
  }
  __syncthreads();
  float acc[16] = {};
  for (int sidx = 0; sidx < 64; ++sidx) {
    float Bv = Bs[sidx][lane];
    float fs = f[sidx];
#pragma unroll
    for (int j = 0; j < 16; ++j)
      acc[j] += (fs * Xs[sidx][grp + 4 * j]) * Bv;
  }
#pragma unroll
  for (int j = 0; j < 16; ++j) {
    int p = grp + 4 * j;
    T[(long)bk * 4096 + p * 64 + lane] = acc[j];
  }
}

// K7: inter-chunk state scan; stores S_prev (state BEFORE each chunk)
__global__ void k_scan(const float* __restrict__ T, const float* __restrict__ cum,
                       float* __restrict__ Sprev) {
  int idx = blockIdx.x * 256 + threadIdx.x;  // 32768
  if (idx >= 32768) return;
  int b = idx >> 12, pn = idx & 4095;
  float sacc = 0.f;
  for (int k = 0; k < 64; ++k) {
    long o = ((long)(b * 64 + k)) * 4096 + pn;
    Sprev[o] = sacc;
    float a = expf(cum[b * 4096 + k * 64 + 63]);
    sacc = a * sacc + T[o];
  }
}

// K8: per-chunk outputs: Y = (M o (C B^T dt)) X + exp(cl) (Sprev C^T) + D*X
__global__ void k_chunkY(const float* __restrict__ xbca, const float* __restrict__ dts,
                         const float* __restrict__ cum, const float* __restrict__ Sprev,
                         const float* __restrict__ Dp, float* __restrict__ Y, int dir) {
  __shared__ float Bs[64][64], Cs[64][64], Xs[64][64], Gs[64][64];
  int bk = blockIdx.x, b = bk >> 6, k = bk & 63;
  int tid = threadIdx.x, lane = tid & 63, grp = tid >> 6;
  long base = (long)b * 4096 + (long)k * 64;
  for (int r = grp; r < 64; r += 4) {
    float dtv = dts[base + r];
    Xs[r][lane] = xbca[(base + r) * 192 + lane];
    Bs[r][(lane + r) & 63] = xbca[(base + r) * 192 + 64 + lane] * dtv;  // XOR-rot swizzle
    Cs[r][lane] = xbca[(base + r) * 192 + 128 + lane];
  }
  float SpR[64];
#pragma unroll
  for (int n = 0; n < 64; ++n) SpR[n] = Sprev[(long)bk * 4096 + lane * 64 + n];
  float clL = cum[base + lane];
  __syncthreads();
  for (int j = 0; j < 16; ++j) {
    int t = grp * 16 + j;
    float g = 0.f;
    if (lane <= t) {
      for (int i = 0; i < 64; ++i) g += Cs[t][i] * Bs[lane][(i + lane) & 63];
      g *= expf(cum[base + t] - clL);
    }
    Gs[t][lane] = g;
  }
  __syncthreads();
  float Dv = Dp[dir];
  for (int j = 0; j < 16; ++j) {
    int t = grp * 16 + j;
    float acc = 0.f;
    for (int sidx = 0; sidx < 64; ++sidx) acc += Gs[t][sidx] * Xs[sidx][lane];
    float inter = 0.f;
#pragma unroll
    for (int n = 0; n < 64; ++n) inter += SpR[n] * Cs[t][n];
    acc += expf(cum[base + t]) * inter + Dv * Xs[t][lane];
    Y[(base + t) * 64 + lane] = acc;
  }
}

// K9: gate with silu(z), RMSNorm, out-proj (64->32), accumulate into s2 (unflip dir1)
__global__ void k_outproj(const float* __restrict__ Y, const float* __restrict__ z,
                          const float* __restrict__ normw, const float* __restrict__ Wout,
                          float* __restrict__ s2, int dir) {
  int idx = blockIdx.x * 256 + threadIdx.x;  // 32768
  if (idx >= 32768) return;
  int b = idx >> 12, l = idx & 4095;
  float yv[64];
  float ssum = 0.f;
#pragma unroll
  for (int p = 0; p < 64; ++p) {
    float zv = z[(long)idx * 64 + p];
    float yy = Y[(long)idx * 64 + p] * siluf(zv);
    yv[p] = yy;
    ssum += yy * yy;
  }
  float r = rsqrtf(ssum * (1.0f / 64.0f) + 1e-5f);
#pragma unroll
  for (int p = 0; p < 64; ++p) yv[p] *= r * normw[dir * 64 + p];
  int lout = dir ? (4095 - l) : l;
  long ob = ((long)b * 4096 + lout) * 32;
  const float* W = Wout + dir * 2048;
  for (int d = 0; d < 32; ++d) {
    float a = 0.f;
#pragma unroll
    for (int p = 0; p < 64; ++p) a += yv[p] * W[p * 32 + d];
    if (dir == 0) s2[ob + d] = a;
    else s2[ob + d] += a;
  }
}

// K10: o3[b,c,l] = sum_d s2[b,l,d]*w[d,c]
__global__ void k_fcout(const float* __restrict__ s2, const float* __restrict__ w,
                        float* __restrict__ o3) {
  __shared__ float t[64][33];
  int b = blockIdx.y, l0 = blockIdx.x * 64;
  int tid = threadIdx.x, lane = tid & 63, grp = tid >> 6;
  for (int i = tid; i < 2048; i += 256)
    t[i >> 5][i & 31] = s2[((long)b * 4096 + l0 + (i >> 5)) * 32 + (i & 31)];
  __syncthreads();
  int cb = grp * 32;
  float acc[32] = {};
  for (int d = 0; d < 32; ++d) {
    float v = t[lane][d];
#pragma unroll
    for (int j = 0; j < 32; ++j) acc[j] += v * w[d * 128 + cb + j];
  }
#pragma unroll
  for (int j = 0; j < 32; ++j)
    o3[((long)b * 128 + cb + j) * 4096 + l0 + lane] = acc[j];
}

// K10b: per-channel sums for BatchNorm
__global__ void k_bnstat(const float* __restrict__ o3, float* __restrict__ stats) {
  int bc = blockIdx.x;  // 1024 = (b,c)
  int tid = threadIdx.x;
  const float* p = o3 + (long)bc * 4096;
  float s = 0.f, q = 0.f;
  for (int i = tid; i < 4096; i += 256) { float v = p[i]; s += v; q += v * v; }
  __shared__ float rs[4], rq[4];
  for (int off = 32; off; off >>= 1) { s += __shfl_down(s, off); q += __shfl_down(q, off); }
  if ((tid & 63) == 0) { rs[tid >> 6] = s; rq[tid >> 6] = q; }
  __syncthreads();
  if (tid == 0) {
    float a = rs[0] + rs[1] + rs[2] + rs[3];
    float b2 = rq[0] + rq[1] + rq[2] + rq[3];
    int c = bc & 127;
    atomicAdd(&stats[c], a);
    atomicAdd(&stats[128 + c], b2);
  }
}

// K12: BN + conv4 (128->128) + sigmoid + gated residual
__global__ void k_final(const float* __restrict__ o3, const float* __restrict__ stats,
                        const float* __restrict__ bng, const float* __restrict__ bnb,
                        const float* __restrict__ w, const float* __restrict__ bias,
                        const float* __restrict__ x, float* __restrict__ out) {
  __shared__ float t[128][64];
  __shared__ float sc[128], sh[128];
  int b = blockIdx.y, l0 = blockIdx.x * 64;
  int tid = threadIdx.x, lane = tid & 63, grp = tid >> 6;
  if (tid < 128) {
    float mu = stats[tid] * (1.0f / 32768.0f);
    float var = stats[128 + tid] * (1.0f / 32768.0f) - mu * mu;
    float r = rsqrtf(var + 1e-5f);
    sc[tid] = r * bng[tid];
    sh[tid] = bnb[tid] - mu * r * bng[tid];
  }
  __syncthreads();
  for (int i = grp; i < 128; i += 4)
    t[i][lane] = o3[((long)b * 128 + i) * 4096 + l0 + lane] * sc[i] + sh[i];
  __syncthreads();
  int ob = grp * 32;
  float acc[32];
#pragma unroll
  for (int j = 0; j < 32; ++j) acc[j] = bias[ob + j];
  for (int i = 0; i < 128; ++i) {
    float v = t[i][lane];
#pragma unroll
    for (int j = 0; j < 32; ++j) acc[j] += v * w[i * 128 + ob + j];
  }
#pragma unroll
  for (int j = 0; j < 32; ++j) {
    long xi = ((long)b * 128 + ob + j) * 4096 + l0 + lane;
    float g = 1.0f / (1.0f + expf(-acc[j]));
    out[xi] = x[xi] * (1.0f + g);
  }
}

extern "C" void kernel_launch(void* const* d_in, const int* in_sizes, int n_in,
                              void* d_out, int out_size, void* d_ws, size_t ws_size,
                              hipStream_t stream) {
  const float* x          = (const float*)d_in[0];
  const float* lin1_w     = (const float*)d_in[1];
  const float* lin1_b     = (const float*)d_in[2];
  const float* dw_w       = (const float*)d_in[3];
  const float* dw_b       = (const float*)d_in[4];
  const float* fc_in_w    = (const float*)d_in[5];
  const float* mam_in_w   = (const float*)d_in[6];
  const float* mam_conv_w = (const float*)d_in[7];
  const float* mam_conv_b = (const float*)d_in[8];
  const float* mam_dt_bias= (const float*)d_in[9];
  const float* mam_A_log  = (const float*)d_in[10];
  const float* mam_D      = (const float*)d_in[11];
  const float* mam_norm_w = (const float*)d_in[12];
  const float* mam_out_w  = (const float*)d_in[13];
  const float* fc_out_w   = (const float*)d_in[14];
  const float* bn_g       = (const float*)d_in[15];
  const float* bn_b       = (const float*)d_in[16];
  const float* conv4_w    = (const float*)d_in[17];
  const float* conv4_b    = (const float*)d_in[18];
  float* out = (float*)d_out;
  float* ws  = (float*)d_ws;

  float* o1   = ws + OFF_O1;
  float* o2   = ws + OFF_O2;
  float* xbc  = ws + OFF_XBC;
  float* Tbuf = ws + OFF_T;
  float* o3   = ws + OFF_O3;
  float* sbuf = ws + OFF_S;
  float* zbuf = ws + OFF_Z;
  float* xbca = ws + OFF_XBCA;
  float* dts  = ws + OFF_DTS;
  float* lda  = ws + OFF_LDA;
  float* cum  = ws + OFF_CUM;
  float* Sprev= ws + OFF_SPREV;
  float* Yraw = ws + OFF_YRAW;
  float* s2   = ws + OFF_S2;
  float* bnst = ws + OFF_BN;

  hipMemsetAsync(bnst, 0, 256 * sizeof(float), stream);

  k_lin1<<<dim3(64, 8), 256, 0, stream>>>(x, lin1_w, lin1_b, o1);
  k_dw<<<(Bn * Cn * Ln) / 256, 256, 0, stream>>>(o1, dw_w, dw_b, o2);
  k_fcin<<<dim3(64, 8), 256, 0, stream>>>(o2, fc_in_w, sbuf);

  for (int dir = 0; dir < 2; ++dir) {
    k_inproj<<<dim3(64, 8), 256, 0, stream>>>(sbuf, mam_in_w, zbuf, xbc, dts, dir);
    k_conv1d<<<(Bn * Ln * 192) / 256, 256, 0, stream>>>(xbc, mam_conv_w, mam_conv_b, xbca, dir);
    k_dt<<<(Bn * Ln) / 256, 256, 0, stream>>>(dts, lda, mam_dt_bias, mam_A_log, dir);
    k_cum<<<8, 64, 0, stream>>>(lda, cum);
    k_chunkT<<<512, 256, 0, stream>>>(xbca, dts, cum, Tbuf);
    k_scan<<<128, 256, 0, stream>>>(Tbuf, cum, Sprev);
    k_chunkY<<<512, 256, 0, stream>>>(xbca, dts, cum, Sprev, mam_D, Yraw, dir);
    k_outproj<<<128, 256, 0, stream>>>(Yraw, zbuf, mam_norm_w, mam_out_w, s2, dir);
  }

  k_fcout<<<dim3(64, 8), 256, 0, stream>>>(s2, fc_out_w, o3);
  k_bnstat<<<1024, 256, 0, stream>>>(o3, bnst);
  k_final<<<dim3(64, 8), 256, 0, stream>>>(o3, bnst, bn_g, bn_b, conv4_w, conv4_b, x, out);
}

// Round 2
// 555.828 us; speedup vs baseline: 3.0869x; 3.0869x over previous
//
#include <hip/hip_runtime.h>
#include <math.h>

// Problem constants
constexpr int Bn = 8, Cn = 128, Ln = 4096;
constexpr int DMn = 32, DIn = 64, DSn = 64;
constexpr int NJ = 257;           // in_proj width: DI + (DI+2DS) + NH

// Workspace layout (float offsets). Lifetime-aliased.
constexpr size_t OFF_O1   = 0;
constexpr size_t OFF_O2   = 4194304;
constexpr size_t OFF_XBC  = 0;
constexpr size_t OFF_T    = 6291456;
constexpr size_t OFF_O3   = 0;
constexpr size_t OFF_S    = 8388608;   // 1048576
constexpr size_t OFF_Z    = 9437184;   // 2097152
constexpr size_t OFF_XBCA = 11534336;  // 6291456
constexpr size_t OFF_DTS  = 17825792;  // 32768
constexpr size_t OFF_LDA  = 17858560;  // 32768
constexpr size_t OFF_CUM  = 17891328;  // 32768
constexpr size_t OFF_SPREV= 17924096;  // 2097152
constexpr size_t OFF_YRAW = 20021248;  // 2097152
constexpr size_t OFF_S2   = 22118400;  // 1048576
constexpr size_t OFF_BN   = 23166976;  // 256

__device__ __forceinline__ float siluf(float v) { return v / (1.0f + expf(-v)); }

// K1: o1[b,o,l] = sum_i x[b,i,l]*w[i,o] + bias[o]
__global__ void k_lin1(const float* __restrict__ x, const float* __restrict__ w,
                       const float* __restrict__ bias, float* __restrict__ o1) {
  __shared__ float xt[128][64];
  int b = blockIdx.y, l0 = blockIdx.x * 64;
  int tid = threadIdx.x, lane = tid & 63, grp = tid >> 6;
  for (int i = grp; i < 128; i += 4)
    xt[i][lane] = x[((long)b * 128 + i) * 4096 + l0 + lane];
  __syncthreads();
  int ob = grp * 32;
  float acc[32];
#pragma unroll
  for (int j = 0; j < 32; ++j) acc[j] = bias[ob + j];
  for (int i = 0; i < 128; ++i) {
    float v = xt[i][lane];
#pragma unroll
    for (int j = 0; j < 32; ++j) acc[j] += v * w[i * 128 + ob + j];
  }
#pragma unroll
  for (int j = 0; j < 32; ++j)
    o1[((long)b * 128 + ob + j) * 4096 + l0 + lane] = acc[j];
}

// K2: depthwise 3x3 SAME + bias + silu
__global__ void k_dw(const float* __restrict__ o1, const float* __restrict__ w,
                     const float* __restrict__ bias, float* __restrict__ o2) {
  int idx = blockIdx.x * 256 + threadIdx.x;
  if (idx >= Bn * Cn * Ln) return;
  int l = idx & 4095, c = (idx >> 12) & 127, b = idx >> 19;
  int h = l >> 6, wq = l & 63;
  float acc = bias[c];
  const float* wp = w + c * 9;
  const float* base = o1 + ((long)b * 128 + c) * 4096;
#pragma unroll
  for (int dh = -1; dh <= 1; ++dh)
#pragma unroll
    for (int dw_ = -1; dw_ <= 1; ++dw_) {
      int hh = h + dh, ww = wq + dw_;
      if (hh >= 0 && hh < 64 && ww >= 0 && ww < 64)
        acc += base[hh * 64 + ww] * wp[(dh + 1) * 3 + (dw_ + 1)];
    }
  o2[idx] = siluf(acc);
}

// K3: s[b,l,d] = sum_c o2[b,c,l]*w[c,d]   (d in 0..31)
__global__ void k_fcin(const float* __restrict__ o2, const float* __restrict__ w,
                       float* __restrict__ s) {
  __shared__ float t[128][64];
  int b = blockIdx.y, l0 = blockIdx.x * 64;
  int tid = threadIdx.x, lane = tid & 63, grp = tid >> 6;
  for (int c = grp; c < 128; c += 4)
    t[c][lane] = o2[((long)b * 128 + c) * 4096 + l0 + lane];
  __syncthreads();
  int db = grp * 8;
  float acc[8] = {};
  for (int c = 0; c < 128; ++c) {
    float v = t[c][lane];
#pragma unroll
    for (int j = 0; j < 8; ++j) acc[j] += v * w[c * 32 + db + j];
  }
#pragma unroll
  for (int j = 0; j < 8; ++j)
    s[((long)b * 4096 + l0 + lane) * 32 + db + j] = acc[j];
}

// K4: in_proj. Each thread owns ONE output column (weights in registers),
// loops over 64 rows; writes fully coalesced.
__global__ void k_inproj(const float* __restrict__ s, const float* __restrict__ Win,
                         float* __restrict__ z, float* __restrict__ xbc,
                         float* __restrict__ dtraw, int dir) {
  __shared__ float st[64][33];
  int b = blockIdx.y, l0 = blockIdx.x * 64;
  int tid = threadIdx.x, lane = tid & 63, grp = tid >> 6;
  for (int i = tid; i < 64 * 32; i += 256) {
    int l = i >> 5, k2 = i & 31;
    int lsrc = dir ? (4095 - (l0 + l)) : (l0 + l);
    st[l][k2] = s[((long)b * 4096 + lsrc) * 32 + k2];
  }
  __syncthreads();
  const float* W = Win + (long)dir * DMn * NJ;
  int col = grp * 64 + lane;  // 0..255
  float wreg[32];
#pragma unroll
  for (int k2 = 0; k2 < 32; ++k2) wreg[k2] = W[k2 * NJ + col];
  long rowbase = (long)b * 4096 + l0;
  for (int r = 0; r < 64; ++r) {
    float a = 0.f;
#pragma unroll
    for (int k2 = 0; k2 < 32; ++k2) a += st[r][k2] * wreg[k2];
    if (col < 64) z[(rowbase + r) * 64 + col] = a;
    else xbc[(rowbase + r) * 192 + (col - 64)] = a;
  }
  if (grp == 0) {  // dt column (index 256)
    float a = 0.f;
#pragma unroll
    for (int k2 = 0; k2 < 32; ++k2) a += st[lane][k2] * W[k2 * NJ + 256];
    dtraw[rowbase + lane] = a;
  }
}

// K5: causal depthwise conv1d (kernel 4) + bias + silu over 192 channels
__global__ void k_conv1d(const float* __restrict__ xbc, const float* __restrict__ w,
                         const float* __restrict__ bias, float* __restrict__ xbca, int dir) {
  long idx = (long)blockIdx.x * 256 + threadIdx.x;
  if (idx >= (long)Bn * Ln * 192) return;
  int c = (int)(idx % 192);
  long bl = idx / 192;
  int l = (int)(bl & 4095);
  const float* wp = w + dir * 768 + c * 4;
  float acc = bias[dir * 192 + c];
#pragma unroll
  for (int j = 0; j < 4; ++j) {
    int ls = l - 3 + j;
    if (ls >= 0) acc += xbc[(bl - (long)(3 - j)) * 192 + c] * wp[j];
  }
  xbca[idx] = siluf(acc);
}

// K5d: dt softplus + log-decay
__global__ void k_dt(float* __restrict__ dts, float* __restrict__ lda,
                     const float* __restrict__ dt_bias, const float* __restrict__ A_log, int dir) {
  int idx = blockIdx.x * 256 + threadIdx.x;
  if (idx >= Bn * Ln) return;
  float v = dts[idx] + dt_bias[dir];
  float sp = (v > 20.f) ? v : log1pf(expf(v));
  dts[idx] = sp;
  lda[idx] = -expf(A_log[dir]) * sp;
}

// K5b: chunk-local cumulative log-decay
__global__ void k_cum(const float* __restrict__ lda, float* __restrict__ cum) {
  int b = blockIdx.x, k = threadIdx.x;  // <<<8,64>>>
  const float* p = lda + b * 4096 + k * 64;
  float* q = cum + b * 4096 + k * 64;
  float c = 0.f;
  for (int t = 0; t < 64; ++t) { c += p[t]; q[t] = c; }
}

// K6: chunk summary T[b,k,p,n] = sum_s exp(cl_end-cl_s)*dt_s*xs_s[p]*B_s[n]
__global__ void k_chunkT(const float* __restrict__ xbca, const float* __restrict__ dts,
                         const float* __restrict__ cum, float* __restrict__ T) {
  __shared__ float Bs[64][64], Xs[64][64];
  __shared__ float f[64];
  int bk = blockIdx.x, b = bk >> 6, k = bk & 63;
  int tid = threadIdx.x, lane = tid & 63, grp = tid >> 6;
  long base = (long)b * 4096 + (long)k * 64;
  for (int r = grp; r < 64; r += 4) {
    Xs[r][lane] = xbca[(base + r) * 192 + lane];
    Bs[r][lane] = xbca[(base + r) * 192 + 64 + lane];
  }
  if (tid < 64) {
    float clend = cum[base + 63];
    f[tid] = expf(clend - cum[base + tid]) * dts[base + tid];
  }
  __syncthreads();
  float acc[16] = {};
  for (int sidx = 0; sidx < 64; ++sidx) {
    float Bv = Bs[sidx][lane];
    float fs = f[sidx];
#pragma unroll
    for (int j = 0; j < 16; ++j)
      acc[j] += (fs * Xs[sidx][grp + 4 * j]) * Bv;
  }
#pragma unroll
  for (int j = 0; j < 16; ++j) {
    int p = grp + 4 * j;
    T[(long)bk * 4096 + p * 64 + lane] = acc[j];
  }
}

// K7: inter-chunk state scan; stores S_prev (state BEFORE each chunk)
__global__ void k_scan(const float* __restrict__ T, const float* __restrict__ cum,
                       float* __restrict__ Sprev) {
  int idx = blockIdx.x * 256 + threadIdx.x;  // 32768
  if (idx >= 32768) return;
  int b = idx >> 12, pn = idx & 4095;
  float sacc = 0.f;
  for (int k = 0; k < 64; ++k) {
    long o = ((long)(b * 64 + k)) * 4096 + pn;
    Sprev[o] = sacc;
    float a = expf(cum[b * 4096 + k * 64 + 63]);
    sacc = a * sacc + T[o];
  }
}

// K8: per-chunk Y. Phased LDS (3 tiles live max, 50KB), 4x4 register tiles,
// no per-thread big arrays (the round-1 version spilled SpR[64] -> 1GB scratch).
__global__ void k_chunkY(const float* __restrict__ xbca, const float* __restrict__ dts,
                         const float* __restrict__ cum, const float* __restrict__ Sprev,
                         const float* __restrict__ Dp, float* __restrict__ Y, int dir) {
  __shared__ float U[64][65];   // B*dt, then Sprev
  __shared__ float V[64][65];   // C, then X
  __shared__ float G[64][65];
  __shared__ float cumS[64];
  int bk = blockIdx.x, b = bk >> 6, k = bk & 63;
  int tid = threadIdx.x, lane = tid & 63, grp = tid >> 6;
  long base = (long)b * 4096 + (long)k * 64;
  for (int r = grp; r < 64; r += 4) {
    float dtv = dts[base + r];
    U[r][lane] = xbca[(base + r) * 192 + 64 + lane] * dtv;   // B*dt
    V[r][lane] = xbca[(base + r) * 192 + 128 + lane];        // C
  }
  if (tid < 64) cumS[tid] = cum[base + tid];
  __syncthreads();
  int tx = tid & 15, ty = tid >> 4;
  int t0 = ty * 4, c0 = tx * 4;
  // phase a: G[t][l] = (l<=t) * exp(ct-cl) * sum_i C[t][i]*Bdt[l][i]
  {
    float g[4][4] = {};
    for (int i = 0; i < 64; ++i) {
      float cv[4], uv[4];
#pragma unroll
      for (int a = 0; a < 4; ++a) cv[a] = V[t0 + a][i];
#pragma unroll
      for (int a = 0; a < 4; ++a) uv[a] = U[c0 + a][i];
#pragma unroll
      for (int a = 0; a < 4; ++a)
#pragma unroll
        for (int bb = 0; bb < 4; ++bb) g[a][bb] += cv[a] * uv[bb];
    }
#pragma unroll
    for (int a = 0; a < 4; ++a) {
      float ct = cumS[t0 + a];
#pragma unroll
      for (int bb = 0; bb < 4; ++bb) {
        int l = c0 + bb;
        G[t0 + a][l] = (l <= t0 + a) ? g[a][bb] * expf(ct - cumS[l]) : 0.f;
      }
    }
  }
  __syncthreads();
  // phase b: U <- Sprev (B*dt dead)
  for (int r = grp; r < 64; r += 4)
    U[r][lane] = Sprev[(long)bk * 4096 + r * 64 + lane];  // U[p][n]
  __syncthreads();
  // inter[t][p] = sum_n Sprev[p][n]*C[t][n]
  float inter[4][4] = {};
  for (int n = 0; n < 64; ++n) {
    float cv[4], sv[4];
#pragma unroll
    for (int a = 0; a < 4; ++a) cv[a] = V[t0 + a][n];
#pragma unroll
    for (int a = 0; a < 4; ++a) sv[a] = U[c0 + a][n];
#pragma unroll
    for (int a = 0; a < 4; ++a)
#pragma unroll
      for (int bb = 0; bb < 4; ++bb) inter[a][bb] += cv[a] * sv[bb];
  }
  __syncthreads();
  // phase c: V <- X (C dead)
  for (int r = grp; r < 64; r += 4)
    V[r][lane] = xbca[(base + r) * 192 + lane];
  __syncthreads();
  // phase d: Y[t][p] = sum_s G[t][s]*X[s][p] + exp(ct)*inter + D*X[t][p]
  float Dv = Dp[dir];
  float acc[4][4];
#pragma unroll
  for (int a = 0; a < 4; ++a) {
    float et = expf(cumS[t0 + a]);
#pragma unroll
    for (int bb = 0; bb < 4; ++bb)
      acc[a][bb] = et * inter[a][bb] + Dv * V[t0 + a][c0 + bb];
  }
  for (int s = 0; s < 64; ++s) {
    float gv[4], xv[4];
#pragma unroll
    for (int a = 0; a < 4; ++a) gv[a] = G[t0 + a][s];
#pragma unroll
    for (int a = 0; a < 4; ++a) xv[a] = V[s][c0 + a];
#pragma unroll
    for (int a = 0; a < 4; ++a)
#pragma unroll
      for (int bb = 0; bb < 4; ++bb) acc[a][bb] += gv[a] * xv[bb];
  }
#pragma unroll
  for (int a = 0; a < 4; ++a) {
    float4 o4 = make_float4(acc[a][0], acc[a][1], acc[a][2], acc[a][3]);
    *(float4*)&Y[(base + t0 + a) * 64 + c0] = o4;
  }
}

// K9: gate+RMSNorm+out-proj fused, LDS-staged (replaces the yv[64] spiller)
__global__ void k_outproj(const float* __restrict__ Y, const float* __restrict__ z,
                          const float* __restrict__ normw, const float* __restrict__ Wout,
                          float* __restrict__ s2, int dir) {
  __shared__ float t[64][65];
  __shared__ float rsc[64];
  int b = blockIdx.y, l0 = blockIdx.x * 64;
  int tid = threadIdx.x, lane = tid & 63, grp = tid >> 6;
  long base = (long)b * 4096 + l0;
  for (int r = grp; r < 64; r += 4) {
    float zv = z[(base + r) * 64 + lane];
    t[r][lane] = Y[(base + r) * 64 + lane] * siluf(zv);
  }
  __syncthreads();
  if (tid < 64) {
    float ss = 0.f;
    for (int p = 0; p < 64; ++p) { float v = t[tid][p]; ss += v * v; }
    rsc[tid] = rsqrtf(ss * (1.0f / 64.0f) + 1e-5f);
  }
  __syncthreads();
  int tx = tid & 31, ty = tid >> 5;  // tx=col, ty in 0..7
  const float* W = Wout + dir * 2048;
  const float* nw = normw + dir * 64;
  float acc[8] = {};
  for (int p = 0; p < 64; ++p) {
    float wv = nw[p] * W[p * 32 + tx];
#pragma unroll
    for (int r8 = 0; r8 < 8; ++r8)
      acc[r8] += t[ty * 8 + r8][p] * wv;
  }
#pragma unroll
  for (int r8 = 0; r8 < 8; ++r8) {
    int r = ty * 8 + r8;
    int l = l0 + r;
    int lout = dir ? (4095 - l) : l;
    long o = ((long)b * 4096 + lout) * 32 + tx;
    float v = acc[r8] * rsc[r];
    if (dir == 0) s2[o] = v;
    else s2[o] += v;
  }
}

// K10: o3[b,c,l] = sum_d s2[b,l,d]*w[d,c]
__global__ void k_fcout(const float* __restrict__ s2, const float* __restrict__ w,
                        float* __restrict__ o3) {
  __shared__ float t[64][33];
  int b = blockIdx.y, l0 = blockIdx.x * 64;
  int tid = threadIdx.x, lane = tid & 63, grp = tid >> 6;
  for (int i = tid; i < 2048; i += 256)
    t[i >> 5][i & 31] = s2[((long)b * 4096 + l0 + (i >> 5)) * 32 + (i & 31)];
  __syncthreads();
  int cb = grp * 32;
  float acc[32] = {};
  for (int d = 0; d < 32; ++d) {
    float v = t[lane][d];
#pragma unroll
    for (int j = 0; j < 32; ++j) acc[j] += v * w[d * 128 + cb + j];
  }
#pragma unroll
  for (int j = 0; j < 32; ++j)
    o3[((long)b * 128 + cb + j) * 4096 + l0 + lane] = acc[j];
}

// K10b: per-channel sums for BatchNorm
__global__ void k_bnstat(const float* __restrict__ o3, float* __restrict__ stats) {
  int bc = blockIdx.x;  // 1024 = (b,c)
  int tid = threadIdx.x;
  const float* p = o3 + (long)bc * 4096;
  float s = 0.f, q = 0.f;
  for (int i = tid; i < 4096; i += 256) { float v = p[i]; s += v; q += v * v; }
  __shared__ float rs[4], rq[4];
  for (int off = 32; off; off >>= 1) { s += __shfl_down(s, off); q += __shfl_down(q, off); }
  if ((tid & 63) == 0) { rs[tid >> 6] = s; rq[tid >> 6] = q; }
  __syncthreads();
  if (tid == 0) {
    float a = rs[0] + rs[1] + rs[2] + rs[3];
    float b2 = rq[0] + rq[1] + rq[2] + rq[3];
    int c = bc & 127;
    atomicAdd(&stats[c], a);
    atomicAdd(&stats[128 + c], b2);
  }
}

// K12: BN + conv4 (128->128) + sigmoid + gated residual
__global__ void k_final(const float* __restrict__ o3, const float* __restrict__ stats,
                        const float* __restrict__ bng, const float* __restrict__ bnb,
                        const float* __restrict__ w, const float* __restrict__ bias,
                        const float* __restrict__ x, float* __restrict__ out) {
  __shared__ float t[128][64];
  __shared__ float sc[128], sh[128];
  int b = blockIdx.y, l0 = blockIdx.x * 64;
  int tid = threadIdx.x, lane = tid & 63, grp = tid >> 6;
  if (tid < 128) {
    float mu = stats[tid] * (1.0f / 32768.0f);
    float var = stats[128 + tid] * (1.0f / 32768.0f) - mu * mu;
    float r = rsqrtf(var + 1e-5f);
    sc[tid] = r * bng[tid];
    sh[tid] = bnb[tid] - mu * r * bng[tid];
  }
  __syncthreads();
  for (int i = grp; i < 128; i += 4)
    t[i][lane] = o3[((long)b * 128 + i) * 4096 + l0 + lane] * sc[i] + sh[i];
  __syncthreads();
  int ob = grp * 32;
  float acc[32];
#pragma unroll
  for (int j = 0; j < 32; ++j) acc[j] = bias[ob + j];
  for (int i = 0; i < 128; ++i) {
    float v = t[i][lane];
#pragma unroll
    for (int j = 0; j < 32; ++j) acc[j] += v * w[i * 128 + ob + j];
  }
#pragma unroll
  for (int j = 0; j < 32; ++j) {
    long xi = ((long)b * 128 + ob + j) * 4096 + l0 + lane;
    float g = 1.0f / (1.0f + expf(-acc[j]));
    out[xi] = x[xi] * (1.0f + g);
  }
}

extern "C" void kernel_launch(void* const* d_in, const int* in_sizes, int n_in,
                              void* d_out, int out_size, void* d_ws, size_t ws_size,
                              hipStream_t stream) {
  const float* x          = (const float*)d_in[0];
  const float* lin1_w     = (const float*)d_in[1];
  const float* lin1_b     = (const float*)d_in[2];
  const float* dw_w       = (const float*)d_in[3];
  const float* dw_b       = (const float*)d_in[4];
  const float* fc_in_w    = (const float*)d_in[5];
  const float* mam_in_w   = (const float*)d_in[6];
  const float* mam_conv_w = (const float*)d_in[7];
  const float* mam_conv_b = (const float*)d_in[8];
  const float* mam_dt_bias= (const float*)d_in[9];
  const float* mam_A_log  = (const float*)d_in[10];
  const float* mam_D      = (const float*)d_in[11];
  const float* mam_norm_w = (const float*)d_in[12];
  const float* mam_out_w  = (const float*)d_in[13];
  const float* fc_out_w   = (const float*)d_in[14];
  const float* bn_g       = (const float*)d_in[15];
  const float* bn_b       = (const float*)d_in[16];
  const float* conv4_w    = (const float*)d_in[17];
  const float* conv4_b    = (const float*)d_in[18];
  float* out = (float*)d_out;
  float* ws  = (float*)d_ws;

  float* o1   = ws + OFF_O1;
  float* o2   = ws + OFF_O2;
  float* xbc  = ws + OFF_XBC;
  float* Tbuf = ws + OFF_T;
  float* o3   = ws + OFF_O3;
  float* sbuf = ws + OFF_S;
  float* zbuf = ws + OFF_Z;
  float* xbca = ws + OFF_XBCA;
  float* dts  = ws + OFF_DTS;
  float* lda  = ws + OFF_LDA;
  float* cum  = ws + OFF_CUM;
  float* Sprev= ws + OFF_SPREV;
  float* Yraw = ws + OFF_YRAW;
  float* s2   = ws + OFF_S2;
  float* bnst = ws + OFF_BN;

  hipMemsetAsync(bnst, 0, 256 * sizeof(float), stream);

  k_lin1<<<dim3(64, 8), 256, 0, stream>>>(x, lin1_w, lin1_b, o1);
  k_dw<<<(Bn * Cn * Ln) / 256, 256, 0, stream>>>(o1, dw_w, dw_b, o2);
  k_fcin<<<dim3(64, 8), 256, 0, stream>>>(o2, fc_in_w, sbuf);

  for (int dir = 0; dir < 2; ++dir) {
    k_inproj<<<dim3(64, 8), 256, 0, stream>>>(sbuf, mam_in_w, zbuf, xbc, dts, dir);
    k_conv1d<<<(Bn * Ln * 192) / 256, 256, 0, stream>>>(xbc, mam_conv_w, mam_conv_b, xbca, dir);
    k_dt<<<(Bn * Ln) / 256, 256, 0, stream>>>(dts, lda, mam_dt_bias, mam_A_log, dir);
    k_cum<<<8, 64, 0, stream>>>(lda, cum);
    k_chunkT<<<512, 256, 0, stream>>>(xbca, dts, cum, Tbuf);
    k_scan<<<128, 256, 0, stream>>>(Tbuf, cum, Sprev);
    k_chunkY<<<512, 256, 0, stream>>>(xbca, dts, cum, Sprev, mam_D, Yraw, dir);
    k_outproj<<<dim3(64, 8), 256, 0, stream>>>(Yraw, zbuf, mam_norm_w, mam_out_w, s2, dir);
  }

  k_fcout<<<dim3(64, 8), 256, 0, stream>>>(s2, fc_out_w, o3);
  k_bnstat<<<1024, 256, 0, stream>>>(o3, bnst);
  k_final<<<dim3(64, 8), 256, 0, stream>>>(o3, bnst, bn_g, bn_b, conv4_w, conv4_b, x, out);
}

// Round 3
// 499.355 us; speedup vs baseline: 3.4360x; 1.1131x over previous
//
#include <hip/hip_runtime.h>
#include <math.h>

// Problem constants
constexpr int Bn = 8, Cn = 128, Ln = 4096;
constexpr int DMn = 32, DIn = 64, DSn = 64;
constexpr int NJ = 257;           // in_proj width: DI + (DI+2DS) + NH

// Workspace layout (float offsets). Lifetime-aliased.
constexpr size_t OFF_O1   = 0;
constexpr size_t OFF_O2   = 4194304;
constexpr size_t OFF_XBC  = 0;
constexpr size_t OFF_T    = 6291456;
constexpr size_t OFF_O3   = 0;
constexpr size_t OFF_S    = 8388608;   // 1048576
constexpr size_t OFF_Z    = 9437184;   // 2097152
constexpr size_t OFF_XBCA = 11534336;  // 6291456
constexpr size_t OFF_DTS  = 17825792;  // 32768
constexpr size_t OFF_CUM  = 17891328;  // 32768
constexpr size_t OFF_SPREV= 17924096;  // 2097152
constexpr size_t OFF_YRAW = 20021248;  // 2097152
constexpr size_t OFF_S2   = 22118400;  // 1048576
constexpr size_t OFF_BN   = 23166976;  // 256

__device__ __forceinline__ float siluf(float v) { return v / (1.0f + expf(-v)); }

// K1: o1[b,o,l] = sum_i x[b,i,l]*w[i,o] + bias[o]
// Weights staged in LDS (two 64-row K-chunks); x read direct coalesced.
__global__ void k_lin1(const float* __restrict__ x, const float* __restrict__ w,
                       const float* __restrict__ bias, float* __restrict__ o1) {
  __shared__ float ws[64][128];  // 32KB
  int b = blockIdx.y, l0 = blockIdx.x * 64;
  int tid = threadIdx.x, lane = tid & 63, grp = tid >> 6;
  int ob = grp * 32;
  float acc[32];
#pragma unroll
  for (int j = 0; j < 32; ++j) acc[j] = bias[ob + j];
  for (int kc = 0; kc < 2; ++kc) {
    for (int t = tid; t < 64 * 128; t += 256)
      ws[t >> 7][t & 127] = w[(kc * 64 + (t >> 7)) * 128 + (t & 127)];
    __syncthreads();
    const float* xp = x + ((long)b * 128 + kc * 64) * 4096 + l0 + lane;
    for (int i = 0; i < 64; ++i) {
      float v = xp[(long)i * 4096];
#pragma unroll
      for (int j = 0; j < 32; ++j) acc[j] += v * ws[i][ob + j];
    }
    __syncthreads();
  }
#pragma unroll
  for (int j = 0; j < 32; ++j)
    o1[((long)b * 128 + ob + j) * 4096 + l0 + lane] = acc[j];
}

// K2: depthwise 3x3 SAME + bias + silu
__global__ void k_dw(const float* __restrict__ o1, const float* __restrict__ w,
                     const float* __restrict__ bias, float* __restrict__ o2) {
  int idx = blockIdx.x * 256 + threadIdx.x;
  if (idx >= Bn * Cn * Ln) return;
  int l = idx & 4095, c = (idx >> 12) & 127, b = idx >> 19;
  int h = l >> 6, wq = l & 63;
  float acc = bias[c];
  const float* wp = w + c * 9;
  const float* base = o1 + ((long)b * 128 + c) * 4096;
#pragma unroll
  for (int dh = -1; dh <= 1; ++dh)
#pragma unroll
    for (int dw_ = -1; dw_ <= 1; ++dw_) {
      int hh = h + dh, ww = wq + dw_;
      if (hh >= 0 && hh < 64 && ww >= 0 && ww < 64)
        acc += base[hh * 64 + ww] * wp[(dh + 1) * 3 + (dw_ + 1)];
    }
  o2[idx] = siluf(acc);
}

// K3: s[b,l,d] = sum_c o2[b,c,l]*w[c,d]  — weights in LDS, o2 direct.
__global__ void k_fcin(const float* __restrict__ o2, const float* __restrict__ w,
                       float* __restrict__ s) {
  __shared__ float ws[128][32];  // 16KB
  int b = blockIdx.y, l0 = blockIdx.x * 64;
  int tid = threadIdx.x, lane = tid & 63, grp = tid >> 6;
  for (int t = tid; t < 4096; t += 256) ws[t >> 5][t & 31] = w[t];
  __syncthreads();
  int db = grp * 8;
  float acc[8] = {};
  const float* o2p = o2 + (long)b * 128 * 4096 + l0 + lane;
  for (int c = 0; c < 128; ++c) {
    float v = o2p[(long)c * 4096];
#pragma unroll
    for (int j = 0; j < 8; ++j) acc[j] += v * ws[c][db + j];
  }
  long ob = ((long)b * 4096 + l0 + lane) * 32 + db;
  *(float4*)&s[ob]     = make_float4(acc[0], acc[1], acc[2], acc[3]);
  *(float4*)&s[ob + 4] = make_float4(acc[4], acc[5], acc[6], acc[7]);
}

// K4: in_proj. Each thread owns ONE output column (weights in registers),
// loops over 64 rows; writes fully coalesced (lanes = consecutive cols).
__global__ void k_inproj(const float* __restrict__ s, const float* __restrict__ Win,
                         float* __restrict__ z, float* __restrict__ xbc,
                         float* __restrict__ dtraw, int dir) {
  __shared__ float st[64][33];
  int b = blockIdx.y, l0 = blockIdx.x * 64;
  int tid = threadIdx.x, lane = tid & 63, grp = tid >> 6;
  for (int i = tid; i < 64 * 32; i += 256) {
    int l = i >> 5, k2 = i & 31;
    int lsrc = dir ? (4095 - (l0 + l)) : (l0 + l);
    st[l][k2] = s[((long)b * 4096 + lsrc) * 32 + k2];
  }
  __syncthreads();
  const float* W = Win + (long)dir * DMn * NJ;
  int col = grp * 64 + lane;  // 0..255
  float wreg[32];
#pragma unroll
  for (int k2 = 0; k2 < 32; ++k2) wreg[k2] = W[k2 * NJ + col];
  long rowbase = (long)b * 4096 + l0;
  for (int r = 0; r < 64; ++r) {
    float a = 0.f;
#pragma unroll
    for (int k2 = 0; k2 < 32; ++k2) a += st[r][k2] * wreg[k2];
    if (col < 64) z[(rowbase + r) * 64 + col] = a;
    else xbc[(rowbase + r) * 192 + (col - 64)] = a;
  }
  if (grp == 0) {  // dt column (index 256)
    float a = 0.f;
#pragma unroll
    for (int k2 = 0; k2 < 32; ++k2) a += st[lane][k2] * W[k2 * NJ + 256];
    dtraw[rowbase + lane] = a;
  }
}

// K5: causal depthwise conv1d (kernel 4) + bias + silu over 192 channels
__global__ void k_conv1d(const float* __restrict__ xbc, const float* __restrict__ w,
                         const float* __restrict__ bias, float* __restrict__ xbca, int dir) {
  long idx = (long)blockIdx.x * 256 + threadIdx.x;
  if (idx >= (long)Bn * Ln * 192) return;
  int c = (int)(idx % 192);
  long bl = idx / 192;
  int l = (int)(bl & 4095);
  const float* wp = w + dir * 768 + c * 4;
  float acc = bias[dir * 192 + c];
#pragma unroll
  for (int j = 0; j < 4; ++j) {
    int ls = l - 3 + j;
    if (ls >= 0) acc += xbc[(bl - (long)(3 - j)) * 192 + c] * wp[j];
  }
  xbca[idx] = siluf(acc);
}

// K5d: dt softplus + chunk-local cumulative log-decay (wave prefix sum).
// One 64-thread wave per (b,chunk).
__global__ void k_dtcum(float* __restrict__ dts, float* __restrict__ cum,
                        const float* __restrict__ dt_bias, const float* __restrict__ A_log,
                        int dir) {
  int b = blockIdx.x >> 6, k = blockIdx.x & 63, t = threadIdx.x;
  int idx = b * 4096 + k * 64 + t;
  float v = dts[idx] + dt_bias[dir];
  float sp = (v > 20.f) ? v : log1pf(expf(v));
  dts[idx] = sp;
  float c = -expf(A_log[dir]) * sp;
#pragma unroll
  for (int off = 1; off < 64; off <<= 1) {
    float u = __shfl_up(c, off);
    if (t >= off) c += u;
  }
  cum[idx] = c;
}

// K6: chunk summary T[b,k,p,n] = sum_s exp(cl_end-cl_s)*dt_s*xs_s[p]*B_s[n]
__global__ void k_chunkT(const float* __restrict__ xbca, const float* __restrict__ dts,
                         const float* __restrict__ cum, float* __restrict__ T) {
  __shared__ float Bs[64][64], Xs[64][64];
  __shared__ float f[64];
  int bk = blockIdx.x, b = bk >> 6, k = bk & 63;
  int tid = threadIdx.x, lane = tid & 63, grp = tid >> 6;
  long base = (long)b * 4096 + (long)k * 64;
  for (int r = grp; r < 64; r += 4) {
    Xs[r][lane] = xbca[(base + r) * 192 + lane];
    Bs[r][lane] = xbca[(base + r) * 192 + 64 + lane];
  }
  if (tid < 64) {
    float clend = cum[base + 63];
    f[tid] = expf(clend - cum[base + tid]) * dts[base + tid];
  }
  __syncthreads();
  float acc[16] = {};
  for (int sidx = 0; sidx < 64; ++sidx) {
    float Bv = Bs[sidx][lane];
    float fs = f[sidx];
#pragma unroll
    for (int j = 0; j < 16; ++j)
      acc[j] += (fs * Xs[sidx][grp + 4 * j]) * Bv;
  }
#pragma unroll
  for (int j = 0; j < 16; ++j) {
    int p = grp + 4 * j;
    T[(long)bk * 4096 + p * 64 + lane] = acc[j];
  }
}

// K7: inter-chunk state scan; stores S_prev (state BEFORE each chunk)
__global__ void k_scan(const float* __restrict__ T, const float* __restrict__ cum,
                       float* __restrict__ Sprev) {
  int idx = blockIdx.x * 256 + threadIdx.x;  // 32768
  if (idx >= 32768) return;
  int b = idx >> 12, pn = idx & 4095;
  float sacc = 0.f;
  for (int k = 0; k < 64; ++k) {
    long o = ((long)(b * 64 + k)) * 4096 + pn;
    Sprev[o] = sacc;
    float a = expf(cum[b * 4096 + k * 64 + 63]);
    sacc = a * sacc + T[o];
  }
}

// K8: per-chunk Y. Phased LDS (3 tiles live max), 4x4 register tiles.
__global__ void k_chunkY(const float* __restrict__ xbca, const float* __restrict__ dts,
                         const float* __restrict__ cum, const float* __restrict__ Sprev,
                         const float* __restrict__ Dp, float* __restrict__ Y, int dir) {
  __shared__ float U[64][65];   // B*dt, then Sprev
  __shared__ float V[64][65];   // C, then X
  __shared__ float G[64][65];
  __shared__ float cumS[64];
  int bk = blockIdx.x, b = bk >> 6, k = bk & 63;
  int tid = threadIdx.x, lane = tid & 63, grp = tid >> 6;
  long base = (long)b * 4096 + (long)k * 64;
  for (int r = grp; r < 64; r += 4) {
    float dtv = dts[base + r];
    U[r][lane] = xbca[(base + r) * 192 + 64 + lane] * dtv;   // B*dt
    V[r][lane] = xbca[(base + r) * 192 + 128 + lane];        // C
  }
  if (tid < 64) cumS[tid] = cum[base + tid];
  __syncthreads();
  int tx = tid & 15, ty = tid >> 4;
  int t0 = ty * 4, c0 = tx * 4;
  {
    float g[4][4] = {};
    for (int i = 0; i < 64; ++i) {
      float cv[4], uv[4];
#pragma unroll
      for (int a = 0; a < 4; ++a) cv[a] = V[t0 + a][i];
#pragma unroll
      for (int a = 0; a < 4; ++a) uv[a] = U[c0 + a][i];
#pragma unroll
      for (int a = 0; a < 4; ++a)
#pragma unroll
        for (int bb = 0; bb < 4; ++bb) g[a][bb] += cv[a] * uv[bb];
    }
#pragma unroll
    for (int a = 0; a < 4; ++a) {
      float ct = cumS[t0 + a];
#pragma unroll
      for (int bb = 0; bb < 4; ++bb) {
        int l = c0 + bb;
        G[t0 + a][l] = (l <= t0 + a) ? g[a][bb] * expf(ct - cumS[l]) : 0.f;
      }
    }
  }
  __syncthreads();
  for (int r = grp; r < 64; r += 4)
    U[r][lane] = Sprev[(long)bk * 4096 + r * 64 + lane];  // U[p][n]
  __syncthreads();
  float inter[4][4] = {};
  for (int n = 0; n < 64; ++n) {
    float cv[4], sv[4];
#pragma unroll
    for (int a = 0; a < 4; ++a) cv[a] = V[t0 + a][n];
#pragma unroll
    for (int a = 0; a < 4; ++a) sv[a] = U[c0 + a][n];
#pragma unroll
    for (int a = 0; a < 4; ++a)
#pragma unroll
      for (int bb = 0; bb < 4; ++bb) inter[a][bb] += cv[a] * sv[bb];
  }
  __syncthreads();
  for (int r = grp; r < 64; r += 4)
    V[r][lane] = xbca[(base + r) * 192 + lane];
  __syncthreads();
  float Dv = Dp[dir];
  float acc[4][4];
#pragma unroll
  for (int a = 0; a < 4; ++a) {
    float et = expf(cumS[t0 + a]);
#pragma unroll
    for (int bb = 0; bb < 4; ++bb)
      acc[a][bb] = et * inter[a][bb] + Dv * V[t0 + a][c0 + bb];
  }
  for (int s = 0; s < 64; ++s) {
    float gv[4], xv[4];
#pragma unroll
    for (int a = 0; a < 4; ++a) gv[a] = G[t0 + a][s];
#pragma unroll
    for (int a = 0; a < 4; ++a) xv[a] = V[s][c0 + a];
#pragma unroll
    for (int a = 0; a < 4; ++a)
#pragma unroll
      for (int bb = 0; bb < 4; ++bb) acc[a][bb] += gv[a] * xv[bb];
  }
#pragma unroll
  for (int a = 0; a < 4; ++a) {
    float4 o4 = make_float4(acc[a][0], acc[a][1], acc[a][2], acc[a][3]);
    *(float4*)&Y[(base + t0 + a) * 64 + c0] = o4;
  }
}

// K9: gate+RMSNorm+out-proj fused; norm_w folded into LDS weights.
__global__ void k_outproj(const float* __restrict__ Y, const float* __restrict__ z,
                          const float* __restrict__ normw, const float* __restrict__ Wout,
                          float* __restrict__ s2, int dir) {
  __shared__ float t[64][65];
  __shared__ float rsc[64];
  __shared__ float Wn[64][32];
  int b = blockIdx.y, l0 = blockIdx.x * 64;
  int tid = threadIdx.x, lane = tid & 63, grp = tid >> 6;
  for (int t2 = tid; t2 < 2048; t2 += 256) {
    int p = t2 >> 5, c = t2 & 31;
    Wn[p][c] = normw[dir * 64 + p] * Wout[dir * 2048 + p * 32 + c];
  }
  long base = (long)b * 4096 + l0;
  for (int r = grp; r < 64; r += 4) {
    float zv = z[(base + r) * 64 + lane];
    t[r][lane] = Y[(base + r) * 64 + lane] * siluf(zv);
  }
  __syncthreads();
  if (tid < 64) {
    float ss = 0.f;
    for (int p = 0; p < 64; ++p) { float v = t[tid][p]; ss += v * v; }
    rsc[tid] = rsqrtf(ss * (1.0f / 64.0f) + 1e-5f);
  }
  __syncthreads();
  int tx = tid & 31, ty = tid >> 5;  // tx=col, ty in 0..7
  float acc[8] = {};
  for (int p = 0; p < 64; ++p) {
    float wv = Wn[p][tx];
#pragma unroll
    for (int r8 = 0; r8 < 8; ++r8)
      acc[r8] += t[ty * 8 + r8][p] * wv;
  }
#pragma unroll
  for (int r8 = 0; r8 < 8; ++r8) {
    int r = ty * 8 + r8;
    int l = l0 + r;
    int lout = dir ? (4095 - l) : l;
    long o = ((long)b * 4096 + lout) * 32 + tx;
    float v = acc[r8] * rsc[r];
    if (dir == 0) s2[o] = v;
    else s2[o] += v;
  }
}

// K10: o3[b,c,l] = sum_d s2[b,l,d]*w[d,c] — weights AND activations in LDS.
__global__ void k_fcout(const float* __restrict__ s2, const float* __restrict__ w,
                        float* __restrict__ o3) {
  __shared__ float t[64][33];
  __shared__ float ws[32][128];  // 16KB
  int b = blockIdx.y, l0 = blockIdx.x * 64;
  int tid = threadIdx.x, lane = tid & 63, grp = tid >> 6;
  for (int i = tid; i < 4096; i += 256) ws[i >> 7][i & 127] = w[i];
  for (int i = tid; i < 2048; i += 256)
    t[i >> 5][i & 31] = s2[((long)b * 4096 + l0 + (i >> 5)) * 32 + (i & 31)];
  __syncthreads();
  int cb = grp * 32;
  float acc[32] = {};
  for (int d = 0; d < 32; ++d) {
    float v = t[lane][d];
#pragma unroll
    for (int j = 0; j < 32; ++j) acc[j] += v * ws[d][cb + j];
  }
#pragma unroll
  for (int j = 0; j < 32; ++j)
    o3[((long)b * 128 + cb + j) * 4096 + l0 + lane] = acc[j];
}

// K10b: per-channel sums for BatchNorm
__global__ void k_bnstat(const float* __restrict__ o3, float* __restrict__ stats) {
  int bc = blockIdx.x;  // 1024 = (b,c)
  int tid = threadIdx.x;
  const float* p = o3 + (long)bc * 4096;
  float s = 0.f, q = 0.f;
  for (int i = tid; i < 4096; i += 256) { float v = p[i]; s += v; q += v * v; }
  __shared__ float rs[4], rq[4];
  for (int off = 32; off; off >>= 1) { s += __shfl_down(s, off); q += __shfl_down(q, off); }
  if ((tid & 63) == 0) { rs[tid >> 6] = s; rq[tid >> 6] = q; }
  __syncthreads();
  if (tid == 0) {
    float a = rs[0] + rs[1] + rs[2] + rs[3];
    float b2 = rq[0] + rq[1] + rq[2] + rq[3];
    int c = bc & 127;
    atomicAdd(&stats[c], a);
    atomicAdd(&stats[128 + c], b2);
  }
}

// K12: BN + conv4 (128->128) + sigmoid + gated residual.
// Weights in LDS K-chunks; o3 read direct with BN applied on the fly.
__global__ void k_final(const float* __restrict__ o3, const float* __restrict__ stats,
                        const float* __restrict__ bng, const float* __restrict__ bnb,
                        const float* __restrict__ w, const float* __restrict__ bias,
                        const float* __restrict__ x, float* __restrict__ out) {
  __shared__ float ws[64][128];  // 32KB
  __shared__ float sc[128], sh[128];
  int b = blockIdx.y, l0 = blockIdx.x * 64;
  int tid = threadIdx.x, lane = tid & 63, grp = tid >> 6;
  if (tid < 128) {
    float mu = stats[tid] * (1.0f / 32768.0f);
    float var = stats[128 + tid] * (1.0f / 32768.0f) - mu * mu;
    float r = rsqrtf(var + 1e-5f);
    sc[tid] = r * bng[tid];
    sh[tid] = bnb[tid] - mu * r * bng[tid];
  }
  int ob = grp * 32;
  float acc[32];
#pragma unroll
  for (int j = 0; j < 32; ++j) acc[j] = bias[ob + j];
  for (int kc = 0; kc < 2; ++kc) {
    __syncthreads();
    for (int t = tid; t < 64 * 128; t += 256)
      ws[t >> 7][t & 127] = w[(kc * 64 + (t >> 7)) * 128 + (t & 127)];
    __syncthreads();
    const float* op = o3 + ((long)b * 128 + kc * 64) * 4096 + l0 + lane;
    for (int i = 0; i < 64; ++i) {
      float v = fmaf(op[(long)i * 4096], sc[kc * 64 + i], sh[kc * 64 + i]);
#pragma unroll
      for (int j = 0; j < 32; ++j) acc[j] += v * ws[i][ob + j];
    }
  }
#pragma unroll
  for (int j = 0; j < 32; ++j) {
    long xi = ((long)b * 128 + ob + j) * 4096 + l0 + lane;
    float g = 1.0f / (1.0f + expf(-acc[j]));
    out[xi] = x[xi] * (1.0f + g);
  }
}

extern "C" void kernel_launch(void* const* d_in, const int* in_sizes, int n_in,
                              void* d_out, int out_size, void* d_ws, size_t ws_size,
                              hipStream_t stream) {
  const float* x          = (const float*)d_in[0];
  const float* lin1_w     = (const float*)d_in[1];
  const float* lin1_b     = (const float*)d_in[2];
  const float* dw_w       = (const float*)d_in[3];
  const float* dw_b       = (const float*)d_in[4];
  const float* fc_in_w    = (const float*)d_in[5];
  const float* mam_in_w   = (const float*)d_in[6];
  const float* mam_conv_w = (const float*)d_in[7];
  const float* mam_conv_b = (const float*)d_in[8];
  const float* mam_dt_bias= (const float*)d_in[9];
  const float* mam_A_log  = (const float*)d_in[10];
  const float* mam_D      = (const float*)d_in[11];
  const float* mam_norm_w = (const float*)d_in[12];
  const float* mam_out_w  = (const float*)d_in[13];
  const float* fc_out_w   = (const float*)d_in[14];
  const float* bn_g       = (const float*)d_in[15];
  const float* bn_b       = (const float*)d_in[16];
  const float* conv4_w    = (const float*)d_in[17];
  const float* conv4_b    = (const float*)d_in[18];
  float* out = (float*)d_out;
  float* ws  = (float*)d_ws;

  float* o1   = ws + OFF_O1;
  float* o2   = ws + OFF_O2;
  float* xbc  = ws + OFF_XBC;
  float* Tbuf = ws + OFF_T;
  float* o3   = ws + OFF_O3;
  float* sbuf = ws + OFF_S;
  float* zbuf = ws + OFF_Z;
  float* xbca = ws + OFF_XBCA;
  float* dts  = ws + OFF_DTS;
  float* cum  = ws + OFF_CUM;
  float* Sprev= ws + OFF_SPREV;
  float* Yraw = ws + OFF_YRAW;
  float* s2   = ws + OFF_S2;
  float* bnst = ws + OFF_BN;

  hipMemsetAsync(bnst, 0, 256 * sizeof(float), stream);

  k_lin1<<<dim3(64, 8), 256, 0, stream>>>(x, lin1_w, lin1_b, o1);
  k_dw<<<(Bn * Cn * Ln) / 256, 256, 0, stream>>>(o1, dw_w, dw_b, o2);
  k_fcin<<<dim3(64, 8), 256, 0, stream>>>(o2, fc_in_w, sbuf);

  for (int dir = 0; dir < 2; ++dir) {
    k_inproj<<<dim3(64, 8), 256, 0, stream>>>(sbuf, mam_in_w, zbuf, xbc, dts, dir);
    k_conv1d<<<(Bn * Ln * 192) / 256, 256, 0, stream>>>(xbc, mam_conv_w, mam_conv_b, xbca, dir);
    k_dtcum<<<512, 64, 0, stream>>>(dts, cum, mam_dt_bias, mam_A_log, dir);
    k_chunkT<<<512, 256, 0, stream>>>(xbca, dts, cum, Tbuf);
    k_scan<<<128, 256, 0, stream>>>(Tbuf, cum, Sprev);
    k_chunkY<<<512, 256, 0, stream>>>(xbca, dts, cum, Sprev, mam_D, Yraw, dir);
    k_outproj<<<dim3(64, 8), 256, 0, stream>>>(Yraw, zbuf, mam_norm_w, mam_out_w, s2, dir);
  }

  k_fcout<<<dim3(64, 8), 256, 0, stream>>>(s2, fc_out_w, o3);
  k_bnstat<<<1024, 256, 0, stream>>>(o3, bnst);
  k_final<<<dim3(64, 8), 256, 0, stream>>>(o3, bnst, bn_g, bn_b, conv4_w, conv4_b, x, out);
}

// Round 4
// 421.210 us; speedup vs baseline: 4.0734x; 1.1855x over previous
//
#include <hip/hip_runtime.h>
#include <math.h>

// Problem constants
constexpr int Bn = 8, Cn = 128, Ln = 4096;
constexpr int DMn = 32, DIn = 64, DSn = 64;
constexpr int NJ = 257;           // in_proj width: DI + (DI+2DS) + NH

// Workspace layout (float offsets). Lifetime-aliased.
constexpr size_t OFF_O1   = 0;
constexpr size_t OFF_O2   = 4194304;
constexpr size_t OFF_XBC  = 0;
constexpr size_t OFF_T    = 6291456;
constexpr size_t OFF_O3   = 0;
constexpr size_t OFF_S    = 8388608;   // 1048576
constexpr size_t OFF_Z    = 9437184;   // 2097152
constexpr size_t OFF_XBCA = 11534336;  // 6291456
constexpr size_t OFF_DTS  = 17825792;  // 32768
constexpr size_t OFF_CUM  = 17891328;  // 32768
constexpr size_t OFF_SPREV= 17924096;  // 2097152
constexpr size_t OFF_YRAW = 20021248;  // 2097152
constexpr size_t OFF_S2   = 22118400;  // 1048576
constexpr size_t OFF_BN   = 23166976;  // 256

__device__ __forceinline__ float siluf(float v) { return v / (1.0f + expf(-v)); }

// K1: o1[b,o,l] = sum_i x[b,i,l]*w[i,o] + bias[o]
// Both operands in LDS, 4x4 micro-tile per thread, 64L x 64C per block.
__global__ void k_lin1(const float* __restrict__ x, const float* __restrict__ w,
                       const float* __restrict__ bias, float* __restrict__ o1) {
  __shared__ float xt[128][64];   // K x L
  __shared__ float wt[128][64];   // K x C
  int b = blockIdx.y, l0 = blockIdx.x * 64, cb = blockIdx.z * 64;
  int tid = threadIdx.x;
  int f4 = (tid & 15) * 4, r0 = tid >> 4;
#pragma unroll
  for (int s = 0; s < 8; ++s) {
    int r = r0 + s * 16;
    *(float4*)&xt[r][f4] = *(const float4*)&x[((long)b * 128 + r) * 4096 + l0 + f4];
    *(float4*)&wt[r][f4] = *(const float4*)&w[r * 128 + cb + f4];
  }
  __syncthreads();
  int tx = tid & 15, ty = tid >> 4;
  int c0 = tx * 4, t0 = ty * 4;
  float acc[4][4];
#pragma unroll
  for (int a = 0; a < 4; ++a) {
    float bv = bias[cb + t0 + a];
#pragma unroll
    for (int q = 0; q < 4; ++q) acc[a][q] = bv;
  }
  for (int k = 0; k < 128; ++k) {
    float4 xv = *(float4*)&xt[k][c0];
    float4 wv = *(float4*)&wt[k][t0];
    float xa[4] = {xv.x, xv.y, xv.z, xv.w};
    float wa[4] = {wv.x, wv.y, wv.z, wv.w};
#pragma unroll
    for (int a = 0; a < 4; ++a)
#pragma unroll
      for (int q = 0; q < 4; ++q) acc[a][q] += wa[a] * xa[q];
  }
#pragma unroll
  for (int a = 0; a < 4; ++a)
    *(float4*)&o1[((long)b * 128 + cb + t0 + a) * 4096 + l0 + c0] =
        make_float4(acc[a][0], acc[a][1], acc[a][2], acc[a][3]);
}

// K2: depthwise 3x3 SAME + bias + silu. One (b,c) plane per block, staged in LDS.
__global__ void k_dw(const float* __restrict__ o1, const float* __restrict__ wgt,
                     const float* __restrict__ bias, float* __restrict__ o2) {
  __shared__ float p[4096];
  int bc = blockIdx.x, c = bc & 127, tid = threadIdx.x;
  const float* src = o1 + (long)bc * 4096;
#pragma unroll
  for (int s4 = 0; s4 < 4; ++s4) {
    int off = s4 * 1024 + tid * 4;
    *(float4*)&p[off] = *(const float4*)&src[off];
  }
  float wr[9];
#pragma unroll
  for (int j = 0; j < 9; ++j) wr[j] = wgt[c * 9 + j];
  float bv = bias[c];
  __syncthreads();
  for (int s = 0; s < 16; ++s) {
    int idx = s * 256 + tid;
    int h = idx >> 6, wq = idx & 63;
    float acc = bv;
#pragma unroll
    for (int dh = -1; dh <= 1; ++dh) {
      int hh = h + dh;
      if (hh < 0 || hh > 63) continue;
#pragma unroll
      for (int dw_ = -1; dw_ <= 1; ++dw_) {
        int ww = wq + dw_;
        if (ww >= 0 && ww < 64)
          acc += p[hh * 64 + ww] * wr[(dh + 1) * 3 + dw_ + 1];
      }
    }
    o2[(long)bc * 4096 + idx] = siluf(acc);
  }
}

// K3: s[b,l,d] = sum_c o2[b,c,l]*w[c,d]  (d<32). 4x2 micro-tiles.
__global__ void k_fcin(const float* __restrict__ o2, const float* __restrict__ w,
                       float* __restrict__ s) {
  __shared__ float xt[128][64];   // K x L
  __shared__ float wt[128][32];   // K x D
  int b = blockIdx.y, l0 = blockIdx.x * 64;
  int tid = threadIdx.x;
  int f4 = (tid & 15) * 4, r0 = tid >> 4;
#pragma unroll
  for (int st = 0; st < 8; ++st) {
    int r = r0 + st * 16;
    *(float4*)&xt[r][f4] = *(const float4*)&o2[((long)b * 128 + r) * 4096 + l0 + f4];
  }
  int f4w = (tid & 7) * 4, rw = tid >> 3;
#pragma unroll
  for (int st = 0; st < 4; ++st) {
    int r = rw + st * 32;
    *(float4*)&wt[r][f4w] = *(const float4*)&w[r * 32 + f4w];
  }
  __syncthreads();
  int tx = tid & 15, ty = tid >> 4;
  int c0 = tx * 4, d0 = ty * 2;
  float acc[2][4] = {};
  for (int k = 0; k < 128; ++k) {
    float4 xv = *(float4*)&xt[k][c0];
    float2 wv = *(float2*)&wt[k][d0];
    float xa[4] = {xv.x, xv.y, xv.z, xv.w};
#pragma unroll
    for (int q = 0; q < 4; ++q) {
      acc[0][q] += wv.x * xa[q];
      acc[1][q] += wv.y * xa[q];
    }
  }
#pragma unroll
  for (int q = 0; q < 4; ++q) {
    long ob = ((long)b * 4096 + l0 + c0 + q) * 32 + d0;
    *(float2*)&s[ob] = make_float2(acc[0][q], acc[1][q]);
  }
}

// K4: in_proj (+ fused dt softplus & chunk-local cumulative log-decay).
__global__ void k_inproj(const float* __restrict__ s, const float* __restrict__ Win,
                         float* __restrict__ z, float* __restrict__ xbc,
                         float* __restrict__ dts, float* __restrict__ cum,
                         const float* __restrict__ dt_bias, const float* __restrict__ A_log,
                         int dir) {
  __shared__ float st[64][33];
  int b = blockIdx.y, l0 = blockIdx.x * 64;
  int tid = threadIdx.x, lane = tid & 63, grp = tid >> 6;
  for (int i = tid; i < 64 * 32; i += 256) {
    int l = i >> 5, k2 = i & 31;
    int lsrc = dir ? (4095 - (l0 + l)) : (l0 + l);
    st[l][k2] = s[((long)b * 4096 + lsrc) * 32 + k2];
  }
  __syncthreads();
  const float* W = Win + (long)dir * DMn * NJ;
  int col = grp * 64 + lane;  // 0..255
  float wreg[32];
#pragma unroll
  for (int k2 = 0; k2 < 32; ++k2) wreg[k2] = W[k2 * NJ + col];
  long rowbase = (long)b * 4096 + l0;
  for (int r = 0; r < 64; ++r) {
    float a = 0.f;
#pragma unroll
    for (int k2 = 0; k2 < 32; ++k2) a += st[r][k2] * wreg[k2];
    if (col < 64) z[(rowbase + r) * 64 + col] = a;
    else xbc[(rowbase + r) * 192 + (col - 64)] = a;
  }
  if (grp == 0) {  // dt column (index 256) + softplus + wave prefix-scan of log-decay
    float a = 0.f;
#pragma unroll
    for (int k2 = 0; k2 < 32; ++k2) a += st[lane][k2] * W[k2 * NJ + 256];
    float v = a + dt_bias[dir];
    float sp = (v > 20.f) ? v : log1pf(expf(v));
    dts[rowbase + lane] = sp;
    float cdecay = -expf(A_log[dir]) * sp;
#pragma unroll
    for (int off = 1; off < 64; off <<= 1) {
      float u = __shfl_up(cdecay, off);
      if (lane >= off) cdecay += u;
    }
    cum[rowbase + lane] = cdecay;
  }
}

// K5: causal depthwise conv1d (kernel 4) + bias + silu over 192 channels
__global__ void k_conv1d(const float* __restrict__ xbc, const float* __restrict__ w,
                         const float* __restrict__ bias, float* __restrict__ xbca, int dir) {
  long idx = (long)blockIdx.x * 256 + threadIdx.x;
  if (idx >= (long)Bn * Ln * 192) return;
  int c = (int)(idx % 192);
  long bl = idx / 192;
  int l = (int)(bl & 4095);
  const float* wp = w + dir * 768 + c * 4;
  float acc = bias[dir * 192 + c];
#pragma unroll
  for (int j = 0; j < 4; ++j) {
    int ls = l - 3 + j;
    if (ls >= 0) acc += xbc[(bl - (long)(3 - j)) * 192 + c] * wp[j];
  }
  xbca[idx] = siluf(acc);
}

// K6: chunk summary T[b,k,p,n] = sum_s exp(cl_end-cl_s)*dt_s*xs_s[p]*B_s[n]
__global__ void k_chunkT(const float* __restrict__ xbca, const float* __restrict__ dts,
                         const float* __restrict__ cum, float* __restrict__ T) {
  __shared__ float Bs[64][64], Xs[64][64];
  __shared__ float f[64];
  int bk = blockIdx.x, b = bk >> 6, k = bk & 63;
  int tid = threadIdx.x, lane = tid & 63, grp = tid >> 6;
  long base = (long)b * 4096 + (long)k * 64;
  for (int r = grp; r < 64; r += 4) {
    Xs[r][lane] = xbca[(base + r) * 192 + lane];
    Bs[r][lane] = xbca[(base + r) * 192 + 64 + lane];
  }
  if (tid < 64) {
    float clend = cum[base + 63];
    f[tid] = expf(clend - cum[base + tid]) * dts[base + tid];
  }
  __syncthreads();
  float acc[16] = {};
  for (int sidx = 0; sidx < 64; ++sidx) {
    float Bv = Bs[sidx][lane];
    float fs = f[sidx];
#pragma unroll
    for (int j = 0; j < 16; ++j)
      acc[j] += (fs * Xs[sidx][grp + 4 * j]) * Bv;
  }
#pragma unroll
  for (int j = 0; j < 16; ++j) {
    int p = grp + 4 * j;
    T[(long)bk * 4096 + p * 64 + lane] = acc[j];
  }
}

// K7: inter-chunk state scan; stores S_prev (state BEFORE each chunk)
__global__ void k_scan(const float* __restrict__ T, const float* __restrict__ cum,
                       float* __restrict__ Sprev) {
  int idx = blockIdx.x * 256 + threadIdx.x;  // 32768
  if (idx >= 32768) return;
  int b = idx >> 12, pn = idx & 4095;
  float sacc = 0.f;
  for (int k = 0; k < 64; ++k) {
    long o = ((long)(b * 64 + k)) * 4096 + pn;
    Sprev[o] = sacc;
    float a = expf(cum[b * 4096 + k * 64 + 63]);
    sacc = a * sacc + T[o];
  }
}

// K8: per-chunk Y. Phased LDS (3 tiles live max), 4x4 register tiles.
__global__ void k_chunkY(const float* __restrict__ xbca, const float* __restrict__ dts,
                         const float* __restrict__ cum, const float* __restrict__ Sprev,
                         const float* __restrict__ Dp, float* __restrict__ Y, int dir) {
  __shared__ float U[64][65];   // B*dt, then Sprev
  __shared__ float V[64][65];   // C, then X
  __shared__ float G[64][65];
  __shared__ float cumS[64];
  int bk = blockIdx.x, b = bk >> 6, k = bk & 63;
  int tid = threadIdx.x, lane = tid & 63, grp = tid >> 6;
  long base = (long)b * 4096 + (long)k * 64;
  for (int r = grp; r < 64; r += 4) {
    float dtv = dts[base + r];
    U[r][lane] = xbca[(base + r) * 192 + 64 + lane] * dtv;   // B*dt
    V[r][lane] = xbca[(base + r) * 192 + 128 + lane];        // C
  }
  if (tid < 64) cumS[tid] = cum[base + tid];
  __syncthreads();
  int tx = tid & 15, ty = tid >> 4;
  int t0 = ty * 4, c0 = tx * 4;
  {
    float g[4][4] = {};
    for (int i = 0; i < 64; ++i) {
      float cv[4], uv[4];
#pragma unroll
      for (int a = 0; a < 4; ++a) cv[a] = V[t0 + a][i];
#pragma unroll
      for (int a = 0; a < 4; ++a) uv[a] = U[c0 + a][i];
#pragma unroll
      for (int a = 0; a < 4; ++a)
#pragma unroll
        for (int bb = 0; bb < 4; ++bb) g[a][bb] += cv[a] * uv[bb];
    }
#pragma unroll
    for (int a = 0; a < 4; ++a) {
      float ct = cumS[t0 + a];
#pragma unroll
      for (int bb = 0; bb < 4; ++bb) {
        int l = c0 + bb;
        G[t0 + a][l] = (l <= t0 + a) ? g[a][bb] * expf(ct - cumS[l]) : 0.f;
      }
    }
  }
  __syncthreads();
  for (int r = grp; r < 64; r += 4)
    U[r][lane] = Sprev[(long)bk * 4096 + r * 64 + lane];  // U[p][n]
  __syncthreads();
  float inter[4][4] = {};
  for (int n = 0; n < 64; ++n) {
    float cv[4], sv[4];
#pragma unroll
    for (int a = 0; a < 4; ++a) cv[a] = V[t0 + a][n];
#pragma unroll
    for (int a = 0; a < 4; ++a) sv[a] = U[c0 + a][n];
#pragma unroll
    for (int a = 0; a < 4; ++a)
#pragma unroll
      for (int bb = 0; bb < 4; ++bb) inter[a][bb] += cv[a] * sv[bb];
  }
  __syncthreads();
  for (int r = grp; r < 64; r += 4)
    V[r][lane] = xbca[(base + r) * 192 + lane];
  __syncthreads();
  float Dv = Dp[dir];
  float acc[4][4];
#pragma unroll
  for (int a = 0; a < 4; ++a) {
    float et = expf(cumS[t0 + a]);
#pragma unroll
    for (int bb = 0; bb < 4; ++bb)
      acc[a][bb] = et * inter[a][bb] + Dv * V[t0 + a][c0 + bb];
  }
  for (int s = 0; s < 64; ++s) {
    float gv[4], xv[4];
#pragma unroll
    for (int a = 0; a < 4; ++a) gv[a] = G[t0 + a][s];
#pragma unroll
    for (int a = 0; a < 4; ++a) xv[a] = V[s][c0 + a];
#pragma unroll
    for (int a = 0; a < 4; ++a)
#pragma unroll
      for (int bb = 0; bb < 4; ++bb) acc[a][bb] += gv[a] * xv[bb];
  }
#pragma unroll
  for (int a = 0; a < 4; ++a) {
    float4 o4 = make_float4(acc[a][0], acc[a][1], acc[a][2], acc[a][3]);
    *(float4*)&Y[(base + t0 + a) * 64 + c0] = o4;
  }
}

// K9: gate+RMSNorm+out-proj fused; norm_w folded into LDS weights.
__global__ void k_outproj(const float* __restrict__ Y, const float* __restrict__ z,
                          const float* __restrict__ normw, const float* __restrict__ Wout,
                          float* __restrict__ s2, int dir) {
  __shared__ float t[64][65];
  __shared__ float rsc[64];
  __shared__ float Wn[64][32];
  int b = blockIdx.y, l0 = blockIdx.x * 64;
  int tid = threadIdx.x, lane = tid & 63, grp = tid >> 6;
  for (int t2 = tid; t2 < 2048; t2 += 256) {
    int p = t2 >> 5, c = t2 & 31;
    Wn[p][c] = normw[dir * 64 + p] * Wout[dir * 2048 + p * 32 + c];
  }
  long base = (long)b * 4096 + l0;
  for (int r = grp; r < 64; r += 4) {
    float zv = z[(base + r) * 64 + lane];
    t[r][lane] = Y[(base + r) * 64 + lane] * siluf(zv);
  }
  __syncthreads();
  if (tid < 64) {
    float ss = 0.f;
    for (int p = 0; p < 64; ++p) { float v = t[tid][p]; ss += v * v; }
    rsc[tid] = rsqrtf(ss * (1.0f / 64.0f) + 1e-5f);
  }
  __syncthreads();
  int tx = tid & 31, ty = tid >> 5;  // tx=col, ty in 0..7
  float acc[8] = {};
  for (int p = 0; p < 64; ++p) {
    float wv = Wn[p][tx];
#pragma unroll
    for (int r8 = 0; r8 < 8; ++r8)
      acc[r8] += t[ty * 8 + r8][p] * wv;
  }
#pragma unroll
  for (int r8 = 0; r8 < 8; ++r8) {
    int r = ty * 8 + r8;
    int l = l0 + r;
    int lout = dir ? (4095 - l) : l;
    long o = ((long)b * 4096 + lout) * 32 + tx;
    float v = acc[r8] * rsc[r];
    if (dir == 0) s2[o] = v;
    else s2[o] += v;
  }
}

// K10: o3[b,c,l] = sum_d s2[b,l,d]*w[d,c].  K=32, 4x4 micro-tiles.
__global__ void k_fcout(const float* __restrict__ s2, const float* __restrict__ w,
                        float* __restrict__ o3) {
  __shared__ float st[32][65];    // K(d) x L (transposed stage)
  __shared__ float wt[32][64];    // K(d) x C
  int b = blockIdx.y, l0 = blockIdx.x * 64, cb = blockIdx.z * 64;
  int tid = threadIdx.x;
  {
    int d = tid & 31, l = tid >> 5;  // 8 l per pass
    for (int st2 = 0; st2 < 8; ++st2) {
      int ll = l + st2 * 8;
      st[d][ll] = s2[((long)b * 4096 + l0 + ll) * 32 + d];
    }
    int f4 = (tid & 15) * 4, r = tid >> 4;
    for (int st2 = 0; st2 < 2; ++st2) {
      int rr = r + st2 * 16;
      *(float4*)&wt[rr][f4] = *(const float4*)&w[rr * 128 + cb + f4];
    }
  }
  __syncthreads();
  int tx = tid & 15, ty = tid >> 4;
  int c0 = tx * 4, t0 = ty * 4;
  float acc[4][4] = {};
  for (int k = 0; k < 32; ++k) {
    float xa[4];
#pragma unroll
    for (int q = 0; q < 4; ++q) xa[q] = st[k][c0 + q];
    float4 wv = *(float4*)&wt[k][t0];
    float wa[4] = {wv.x, wv.y, wv.z, wv.w};
#pragma unroll
    for (int a = 0; a < 4; ++a)
#pragma unroll
      for (int q = 0; q < 4; ++q) acc[a][q] += wa[a] * xa[q];
  }
#pragma unroll
  for (int a = 0; a < 4; ++a)
    *(float4*)&o3[((long)b * 128 + cb + t0 + a) * 4096 + l0 + c0] =
        make_float4(acc[a][0], acc[a][1], acc[a][2], acc[a][3]);
}

// K10b: per-channel sums for BatchNorm
__global__ void k_bnstat(const float* __restrict__ o3, float* __restrict__ stats) {
  int bc = blockIdx.x;  // 1024 = (b,c)
  int tid = threadIdx.x;
  const float* p = o3 + (long)bc * 4096;
  float s = 0.f, q = 0.f;
  for (int i = tid; i < 4096; i += 256) { float v = p[i]; s += v; q += v * v; }
  __shared__ float rs[4], rq[4];
  for (int off = 32; off; off >>= 1) { s += __shfl_down(s, off); q += __shfl_down(q, off); }
  if ((tid & 63) == 0) { rs[tid >> 6] = s; rq[tid >> 6] = q; }
  __syncthreads();
  if (tid == 0) {
    float a = rs[0] + rs[1] + rs[2] + rs[3];
    float b2 = rq[0] + rq[1] + rq[2] + rq[3];
    int c = bc & 127;
    atomicAdd(&stats[c], a);
    atomicAdd(&stats[128 + c], b2);
  }
}

// K12: BN + conv4 (128->128) + sigmoid + gated residual. 4x4 micro-tiles.
__global__ void k_final(const float* __restrict__ o3, const float* __restrict__ stats,
                        const float* __restrict__ bng, const float* __restrict__ bnb,
                        const float* __restrict__ w, const float* __restrict__ bias,
                        const float* __restrict__ x, float* __restrict__ out) {
  __shared__ float xt[128][64];
  __shared__ float wt[128][64];
  __shared__ float sc[128], sh[128];
  int b = blockIdx.y, l0 = blockIdx.x * 64, cb = blockIdx.z * 64;
  int tid = threadIdx.x;
  if (tid < 128) {
    float mu = stats[tid] * (1.0f / 32768.0f);
    float var = stats[128 + tid] * (1.0f / 32768.0f) - mu * mu;
    float r = rsqrtf(var + 1e-5f);
    sc[tid] = r * bng[tid];
    sh[tid] = bnb[tid] - mu * r * bng[tid];
  }
  __syncthreads();
  int f4 = (tid & 15) * 4, r0 = tid >> 4;
#pragma unroll
  for (int s = 0; s < 8; ++s) {
    int r = r0 + s * 16;
    float4 v = *(const float4*)&o3[((long)b * 128 + r) * 4096 + l0 + f4];
    float scr = sc[r], shr = sh[r];
    *(float4*)&xt[r][f4] = make_float4(fmaf(v.x, scr, shr), fmaf(v.y, scr, shr),
                                       fmaf(v.z, scr, shr), fmaf(v.w, scr, shr));
    *(float4*)&wt[r][f4] = *(const float4*)&w[r * 128 + cb + f4];
  }
  __syncthreads();
  int tx = tid & 15, ty = tid >> 4;
  int c0 = tx * 4, t0 = ty * 4;
  float acc[4][4];
#pragma unroll
  for (int a = 0; a < 4; ++a) {
    float bv = bias[cb + t0 + a];
#pragma unroll
    for (int q = 0; q < 4; ++q) acc[a][q] = bv;
  }
  for (int k = 0; k < 128; ++k) {
    float4 xv = *(float4*)&xt[k][c0];
    float4 wv = *(float4*)&wt[k][t0];
    float xa[4] = {xv.x, xv.y, xv.z, xv.w};
    float wa[4] = {wv.x, wv.y, wv.z, wv.w};
#pragma unroll
    for (int a = 0; a < 4; ++a)
#pragma unroll
      for (int q = 0; q < 4; ++q) acc[a][q] += wa[a] * xa[q];
  }
#pragma unroll
  for (int a = 0; a < 4; ++a) {
    long xi = ((long)b * 128 + cb + t0 + a) * 4096 + l0 + c0;
    float4 xv = *(const float4*)&x[xi];
    float4 o4;
    o4.x = xv.x * (1.0f + 1.0f / (1.0f + expf(-acc[a][0])));
    o4.y = xv.y * (1.0f + 1.0f / (1.0f + expf(-acc[a][1])));
    o4.z = xv.z * (1.0f + 1.0f / (1.0f + expf(-acc[a][2])));
    o4.w = xv.w * (1.0f + 1.0f / (1.0f + expf(-acc[a][3])));
    *(float4*)&out[xi] = o4;
  }
}

extern "C" void kernel_launch(void* const* d_in, const int* in_sizes, int n_in,
                              void* d_out, int out_size, void* d_ws, size_t ws_size,
                              hipStream_t stream) {
  const float* x          = (const float*)d_in[0];
  const float* lin1_w     = (const float*)d_in[1];
  const float* lin1_b     = (const float*)d_in[2];
  const float* dw_w       = (const float*)d_in[3];
  const float* dw_b       = (const float*)d_in[4];
  const float* fc_in_w    = (const float*)d_in[5];
  const float* mam_in_w   = (const float*)d_in[6];
  const float* mam_conv_w = (const float*)d_in[7];
  const float* mam_conv_b = (const float*)d_in[8];
  const float* mam_dt_bias= (const float*)d_in[9];
  const float* mam_A_log  = (const float*)d_in[10];
  const float* mam_D      = (const float*)d_in[11];
  const float* mam_norm_w = (const float*)d_in[12];
  const float* mam_out_w  = (const float*)d_in[13];
  const float* fc_out_w   = (const float*)d_in[14];
  const float* bn_g       = (const float*)d_in[15];
  const float* bn_b       = (const float*)d_in[16];
  const float* conv4_w    = (const float*)d_in[17];
  const float* conv4_b    = (const float*)d_in[18];
  float* out = (float*)d_out;
  float* ws  = (float*)d_ws;

  float* o1   = ws + OFF_O1;
  float* o2   = ws + OFF_O2;
  float* xbc  = ws + OFF_XBC;
  float* Tbuf = ws + OFF_T;
  float* o3   = ws + OFF_O3;
  float* sbuf = ws + OFF_S;
  float* zbuf = ws + OFF_Z;
  float* xbca = ws + OFF_XBCA;
  float* dts  = ws + OFF_DTS;
  float* cum  = ws + OFF_CUM;
  float* Sprev= ws + OFF_SPREV;
  float* Yraw = ws + OFF_YRAW;
  float* s2   = ws + OFF_S2;
  float* bnst = ws + OFF_BN;

  hipMemsetAsync(bnst, 0, 256 * sizeof(float), stream);

  k_lin1<<<dim3(64, 8, 2), 256, 0, stream>>>(x, lin1_w, lin1_b, o1);
  k_dw<<<1024, 256, 0, stream>>>(o1, dw_w, dw_b, o2);
  k_fcin<<<dim3(64, 8), 256, 0, stream>>>(o2, fc_in_w, sbuf);

  for (int dir = 0; dir < 2; ++dir) {
    k_inproj<<<dim3(64, 8), 256, 0, stream>>>(sbuf, mam_in_w, zbuf, xbc, dts, cum,
                                              mam_dt_bias, mam_A_log, dir);
    k_conv1d<<<(Bn * Ln * 192) / 256, 256, 0, stream>>>(xbc, mam_conv_w, mam_conv_b, xbca, dir);
    k_chunkT<<<512, 256, 0, stream>>>(xbca, dts, cum, Tbuf);
    k_scan<<<128, 256, 0, stream>>>(Tbuf, cum, Sprev);
    k_chunkY<<<512, 256, 0, stream>>>(xbca, dts, cum, Sprev, mam_D, Yraw, dir);
    k_outproj<<<dim3(64, 8), 256, 0, stream>>>(Yraw, zbuf, mam_norm_w, mam_out_w, s2, dir);
  }

  k_fcout<<<dim3(64, 8, 2), 256, 0, stream>>>(s2, fc_out_w, o3);
  k_bnstat<<<1024, 256, 0, stream>>>(o3, bnst);
  k_final<<<dim3(64, 8, 2), 256, 0, stream>>>(o3, bnst, bn_g, bn_b, conv4_w, conv4_b, x, out);
}

// Round 5
// 393.453 us; speedup vs baseline: 4.3608x; 1.0705x over previous
//
#include <hip/hip_runtime.h>
#include <math.h>

// Problem constants
constexpr int Bn = 8, Cn = 128, Ln = 4096;

// Workspace layout (float offsets). ws_size = 256 MiB so little aliasing needed.
constexpr size_t OFF_O1   = 0;          // 4,194,304  (o1; later o3)
constexpr size_t OFF_O2   = 4194304;    // 4,194,304
constexpr size_t OFF_S    = 8388608;    // 1,048,576
constexpr size_t OFF_Z    = 9437184;    // 4,194,304  (2 dirs x 2,097,152)
constexpr size_t OFF_XBCA = 13631488;   // 12,582,912 (2 dirs x 6,291,456)
constexpr size_t OFF_DTS  = 26214400;   // 65,536
constexpr size_t OFF_CUM  = 26279936;   // 65,536
constexpr size_t OFF_T    = 26345472;   // 4,194,304  (2 dirs x 2,097,152)
constexpr size_t OFF_SPREV= 30539776;   // 4,194,304
constexpr size_t OFF_S2A  = 34734080;   // 1,048,576
constexpr size_t OFF_S2B  = 35782656;   // 1,048,576
constexpr size_t OFF_BN   = 36831232;   // 256
constexpr size_t OFF_O3   = 0;          // alias o1 (dead after k_dw)

constexpr long ZSTRIDE = 2097152;   // per-dir z stride
constexpr long XSTRIDE = 6291456;   // per-dir xbca stride
constexpr long TSTRIDE = 2097152;   // per-dir T/Sprev stride

__device__ __forceinline__ float siluf(float v) { return v / (1.0f + expf(-v)); }

// K1: o1[b,o,l] = sum_i x[b,i,l]*w[i,o] + bias[o]. 4x4 micro-tiles, 64Lx64C.
__global__ void k_lin1(const float* __restrict__ x, const float* __restrict__ w,
                       const float* __restrict__ bias, float* __restrict__ o1) {
  __shared__ float xt[128][64];
  __shared__ float wt[128][64];
  int b = blockIdx.y, l0 = blockIdx.x * 64, cb = blockIdx.z * 64;
  int tid = threadIdx.x;
  int f4 = (tid & 15) * 4, r0 = tid >> 4;
#pragma unroll
  for (int s = 0; s < 8; ++s) {
    int r = r0 + s * 16;
    *(float4*)&xt[r][f4] = *(const float4*)&x[((long)b * 128 + r) * 4096 + l0 + f4];
    *(float4*)&wt[r][f4] = *(const float4*)&w[r * 128 + cb + f4];
  }
  __syncthreads();
  int tx = tid & 15, ty = tid >> 4;
  int c0 = tx * 4, t0 = ty * 4;
  float acc[4][4];
#pragma unroll
  for (int a = 0; a < 4; ++a) {
    float bv = bias[cb + t0 + a];
#pragma unroll
    for (int q = 0; q < 4; ++q) acc[a][q] = bv;
  }
  for (int k = 0; k < 128; ++k) {
    float4 xv = *(float4*)&xt[k][c0];
    float4 wv = *(float4*)&wt[k][t0];
    float xa[4] = {xv.x, xv.y, xv.z, xv.w};
    float wa[4] = {wv.x, wv.y, wv.z, wv.w};
#pragma unroll
    for (int a = 0; a < 4; ++a)
#pragma unroll
      for (int q = 0; q < 4; ++q) acc[a][q] += wa[a] * xa[q];
  }
#pragma unroll
  for (int a = 0; a < 4; ++a)
    *(float4*)&o1[((long)b * 128 + cb + t0 + a) * 4096 + l0 + c0] =
        make_float4(acc[a][0], acc[a][1], acc[a][2], acc[a][3]);
}

// K2: depthwise 3x3 SAME + bias + silu. Register-window version: each thread
// computes a 4x4 output patch from an LDS-staged plane.
__global__ void k_dw(const float* __restrict__ o1, const float* __restrict__ wgt,
                     const float* __restrict__ bias, float* __restrict__ o2) {
  __shared__ float p[4096];
  int bc = blockIdx.x, c = bc & 127, tid = threadIdx.x;
  const float* src = o1 + (long)bc * 4096;
#pragma unroll
  for (int s4 = 0; s4 < 4; ++s4) {
    int off = s4 * 1024 + tid * 4;
    *(float4*)&p[off] = *(const float4*)&src[off];
  }
  float wr[9];
#pragma unroll
  for (int j = 0; j < 9; ++j) wr[j] = wgt[c * 9 + j];
  float bv = bias[c];
  __syncthreads();
  int wg = tid & 15, hs = tid >> 4;
  int w0 = wg * 4, h0 = hs * 4;
  float in[6][6];
#pragma unroll
  for (int ri = 0; ri < 6; ++ri) {
    int h = h0 - 1 + ri;
    if (h < 0 || h > 63) {
#pragma unroll
      for (int ci = 0; ci < 6; ++ci) in[ri][ci] = 0.f;
    } else {
      float4 cc = *(float4*)&p[h * 64 + w0];
      in[ri][1] = cc.x; in[ri][2] = cc.y; in[ri][3] = cc.z; in[ri][4] = cc.w;
      in[ri][0] = (w0 > 0) ? p[h * 64 + w0 - 1] : 0.f;
      in[ri][5] = (w0 < 60) ? p[h * 64 + w0 + 4] : 0.f;
    }
  }
#pragma unroll
  for (int r = 0; r < 4; ++r) {
    float oc[4];
#pragma unroll
    for (int q = 0; q < 4; ++q) {
      float acc = bv;
#pragma unroll
      for (int dh = 0; dh < 3; ++dh)
#pragma unroll
        for (int dq = 0; dq < 3; ++dq)
          acc += in[r + dh][q + dq] * wr[dh * 3 + dq];
      oc[q] = siluf(acc);
    }
    *(float4*)&o2[(long)bc * 4096 + (h0 + r) * 64 + w0] =
        make_float4(oc[0], oc[1], oc[2], oc[3]);
  }
}

// K3: s[b,l,d] = sum_c o2[b,c,l]*w[c,d]  (d<32). 4x2 micro-tiles.
__global__ void k_fcin(const float* __restrict__ o2, const float* __restrict__ w,
                       float* __restrict__ s) {
  __shared__ float xt[128][64];
  __shared__ float wt[128][32];
  int b = blockIdx.y, l0 = blockIdx.x * 64;
  int tid = threadIdx.x;
  int f4 = (tid & 15) * 4, r0 = tid >> 4;
#pragma unroll
  for (int st = 0; st < 8; ++st) {
    int r = r0 + st * 16;
    *(float4*)&xt[r][f4] = *(const float4*)&o2[((long)b * 128 + r) * 4096 + l0 + f4];
  }
  int f4w = (tid & 7) * 4, rw = tid >> 3;
#pragma unroll
  for (int st = 0; st < 4; ++st) {
    int r = rw + st * 32;
    *(float4*)&wt[r][f4w] = *(const float4*)&w[r * 32 + f4w];
  }
  __syncthreads();
  int tx = tid & 15, ty = tid >> 4;
  int c0 = tx * 4, d0 = ty * 2;
  float acc[2][4] = {};
  for (int k = 0; k < 128; ++k) {
    float4 xv = *(float4*)&xt[k][c0];
    float2 wv = *(float2*)&wt[k][d0];
    float xa[4] = {xv.x, xv.y, xv.z, xv.w};
#pragma unroll
    for (int q = 0; q < 4; ++q) {
      acc[0][q] += wv.x * xa[q];
      acc[1][q] += wv.y * xa[q];
    }
  }
#pragma unroll
  for (int q = 0; q < 4; ++q) {
    long ob = ((long)b * 4096 + l0 + c0 + q) * 32 + d0;
    *(float2*)&s[ob] = make_float2(acc[0][q], acc[1][q]);
  }
}

// K4: in_proj + causal conv1d + silu + dt softplus + cum, both dirs, fused.
// xBC never leaves the block (3-row halo recomputed in-LDS).
__global__ void k_inprojconv(const float* __restrict__ s, const float* __restrict__ Win,
                             const float* __restrict__ conv_w, const float* __restrict__ conv_b,
                             const float* __restrict__ dt_bias, const float* __restrict__ A_log,
                             float* __restrict__ z, float* __restrict__ xbca,
                             float* __restrict__ dts, float* __restrict__ cum) {
  __shared__ float st[67][36];      // s rows for seq idx l0-3..l0+63 (flip-resolved)
  __shared__ float xbcL[67][192];
  __shared__ float wT[4][192];
  __shared__ float bcv[192];
  int dir = blockIdx.z;
  int b = blockIdx.y, l0 = blockIdx.x * 64;
  int tid = threadIdx.x;
  if (tid < 192) {
    bcv[tid] = conv_b[dir * 192 + tid];
#pragma unroll
    for (int j = 0; j < 4; ++j) wT[j][tid] = conv_w[dir * 768 + tid * 4 + j];
  }
  for (int i = tid; i < 67 * 32; i += 256) {
    int rr = i >> 5, k2 = i & 31;
    int l = l0 - 3 + rr;
    float v = 0.f;
    if (l >= 0) {
      int lsrc = dir ? (4095 - l) : l;
      v = s[((long)b * 4096 + lsrc) * 32 + k2];
    }
    st[rr][k2] = v;
  }
  __syncthreads();
  const float* W = Win + (long)dir * 32 * 257;
  float wreg[32];
#pragma unroll
  for (int k2 = 0; k2 < 32; ++k2) wreg[k2] = W[k2 * 257 + tid];
  long rowbase = (long)b * 4096 + l0;
  if (tid < 64) {
    float* zp = z + (long)dir * ZSTRIDE;
    for (int r = 0; r < 64; ++r) {
      float a = 0.f;
#pragma unroll
      for (int k2 = 0; k2 < 32; k2 += 4) {
        float4 sv = *(float4*)&st[r + 3][k2];
        a += sv.x * wreg[k2] + sv.y * wreg[k2 + 1] + sv.z * wreg[k2 + 2] + sv.w * wreg[k2 + 3];
      }
      zp[(rowbase + r) * 64 + tid] = a;
    }
    // dt column (256) + softplus + wave prefix scan of log-decay
    float a = 0.f;
#pragma unroll
    for (int k2 = 0; k2 < 32; ++k2) a += st[tid + 3][k2] * W[k2 * 257 + 256];
    float v = a + dt_bias[dir];
    float sp = (v > 20.f) ? v : log1pf(expf(v));
    dts[dir * 32768 + rowbase + tid] = sp;
    float cd = -expf(A_log[dir]) * sp;
#pragma unroll
    for (int off = 1; off < 64; off <<= 1) {
      float u = __shfl_up(cd, off);
      if (tid >= off) cd += u;
    }
    cum[dir * 32768 + rowbase + tid] = cd;
  } else {
    int c = tid - 64;   // xbc col 0..191
    for (int r = 0; r < 67; ++r) {
      float a = 0.f;
#pragma unroll
      for (int k2 = 0; k2 < 32; k2 += 4) {
        float4 sv = *(float4*)&st[r][k2];
        a += sv.x * wreg[k2] + sv.y * wreg[k2 + 1] + sv.z * wreg[k2 + 2] + sv.w * wreg[k2 + 3];
      }
      xbcL[r][c] = a;
    }
  }
  __syncthreads();
  float* xp = xbca + (long)dir * XSTRIDE;
  for (int i = tid; i < 64 * 48; i += 256) {
    int r = i / 48, cq = (i - r * 48) * 4;
    float4 acc4 = *(float4*)&bcv[cq];
#pragma unroll
    for (int j = 0; j < 4; ++j) {
      float4 xv = *(float4*)&xbcL[r + j][cq];
      float4 wv = *(float4*)&wT[j][cq];
      acc4.x += xv.x * wv.x; acc4.y += xv.y * wv.y;
      acc4.z += xv.z * wv.z; acc4.w += xv.w * wv.w;
    }
    *(float4*)&xp[(rowbase + r) * 192 + cq] =
        make_float4(siluf(acc4.x), siluf(acc4.y), siluf(acc4.z), siluf(acc4.w));
  }
}

// K6: chunk summary T[p][n] = sum_s f_s*X_s[p]*B_s[n], f folded into X staging.
__global__ void k_chunkT(const float* __restrict__ xbca, const float* __restrict__ dts,
                         const float* __restrict__ cum, float* __restrict__ T) {
  __shared__ float Xs[64][65], Bs[64][65];
  int dir = blockIdx.y;
  int bk = blockIdx.x, b = bk >> 6, k = bk & 63;
  int tid = threadIdx.x, lane = tid & 63, grp = tid >> 6;
  const float* xp = xbca + (long)dir * XSTRIDE;
  const float* dtp = dts + dir * 32768;
  const float* cp = cum + dir * 32768;
  long base = (long)b * 4096 + (long)k * 64;
  float clend = cp[base + 63];
  for (int r = grp; r < 64; r += 4) {
    float f = expf(clend - cp[base + r]) * dtp[base + r];
    Xs[r][lane] = xp[(base + r) * 192 + lane] * f;
    Bs[r][lane] = xp[(base + r) * 192 + 64 + lane];
  }
  __syncthreads();
  int tx = tid & 15, ty = tid >> 4;
  int p0 = ty * 4, n0 = tx * 4;
  float acc[4][4] = {};
  for (int s = 0; s < 64; ++s) {
    float4 xv = *(float4*)&Xs[s][p0];
    float4 bv = *(float4*)&Bs[s][n0];
    float xa[4] = {xv.x, xv.y, xv.z, xv.w};
    float ba[4] = {bv.x, bv.y, bv.z, bv.w};
#pragma unroll
    for (int a = 0; a < 4; ++a)
#pragma unroll
      for (int q = 0; q < 4; ++q) acc[a][q] += xa[a] * ba[q];
  }
#pragma unroll
  for (int a = 0; a < 4; ++a)
    *(float4*)&T[(long)dir * TSTRIDE + (long)bk * 4096 + (p0 + a) * 64 + n0] =
        make_float4(acc[a][0], acc[a][1], acc[a][2], acc[a][3]);
}

// K7: inter-chunk state scan (both dirs; 256 blocks = full CU coverage)
__global__ void k_scan(const float* __restrict__ T, const float* __restrict__ cum,
                       float* __restrict__ Sprev) {
  int idx = blockIdx.x * 256 + threadIdx.x;   // 65536
  int dir = idx >> 15, rem = idx & 32767;
  int b = rem >> 12, pn = rem & 4095;
  const float* Tp = T + (long)dir * TSTRIDE;
  float* Sp = Sprev + (long)dir * TSTRIDE;
  const float* cp = cum + dir * 32768 + b * 4096;
  float sacc = 0.f;
  for (int k = 0; k < 64; ++k) {
    long o = ((long)(b * 64 + k)) * 4096 + pn;
    Sp[o] = sacc;
    sacc = expf(cp[k * 64 + 63]) * sacc + Tp[o];
  }
}

// K8: per-chunk Y + gate + RMSNorm + out-proj, fully fused. Y never hits HBM.
__global__ void k_chunkYout(const float* __restrict__ xbca, const float* __restrict__ dts,
                            const float* __restrict__ cum, const float* __restrict__ Sprev,
                            const float* __restrict__ Dp, const float* __restrict__ z,
                            const float* __restrict__ normw, const float* __restrict__ Wout,
                            float* __restrict__ s2a, float* __restrict__ s2b) {
  __shared__ float U[64][65];   // B*dt -> Sprev
  __shared__ float V[64][65];   // C -> X -> Wn
  __shared__ float G[64][65];   // G -> gated Y
  __shared__ float cumS[64];
  __shared__ float part[4][64];
  __shared__ float rsc[64];
  int dir = blockIdx.y;
  int bk = blockIdx.x, b = bk >> 6, k = bk & 63;
  int tid = threadIdx.x, lane = tid & 63, grp = tid >> 6;
  const float* xp = xbca + (long)dir * XSTRIDE;
  const float* dtp = dts + dir * 32768;
  const float* cp = cum + dir * 32768;
  const float* Sp = Sprev + (long)dir * TSTRIDE;
  const float* zp = z + (long)dir * ZSTRIDE;
  long base = (long)b * 4096 + (long)k * 64;
  for (int r = grp; r < 64; r += 4) {
    float dtv = dtp[base + r];
    U[r][lane] = xp[(base + r) * 192 + 64 + lane] * dtv;   // B*dt
    V[r][lane] = xp[(base + r) * 192 + 128 + lane];        // C
  }
  if (tid < 64) cumS[tid] = cp[base + tid];
  __syncthreads();
  int tx = tid & 15, ty = tid >> 4;
  int t0 = ty * 4, c0 = tx * 4;
  {
    float g[4][4] = {};
    for (int i = 0; i < 64; ++i) {
      float cv[4], uv[4];
#pragma unroll
      for (int a = 0; a < 4; ++a) cv[a] = V[t0 + a][i];
#pragma unroll
      for (int a = 0; a < 4; ++a) uv[a] = U[c0 + a][i];
#pragma unroll
      for (int a = 0; a < 4; ++a)
#pragma unroll
        for (int bb = 0; bb < 4; ++bb) g[a][bb] += cv[a] * uv[bb];
    }
#pragma unroll
    for (int a = 0; a < 4; ++a) {
      float ct = cumS[t0 + a];
#pragma unroll
      for (int bb = 0; bb < 4; ++bb) {
        int l = c0 + bb;
        G[t0 + a][l] = (l <= t0 + a) ? g[a][bb] * expf(ct - cumS[l]) : 0.f;
      }
    }
  }
  __syncthreads();
  for (int r = grp; r < 64; r += 4)
    U[r][lane] = Sp[(long)bk * 4096 + r * 64 + lane];  // U[p][n]
  __syncthreads();
  float inter[4][4] = {};
  for (int n = 0; n < 64; ++n) {
    float cv[4], sv[4];
#pragma unroll
    for (int a = 0; a < 4; ++a) cv[a] = V[t0 + a][n];
#pragma unroll
    for (int a = 0; a < 4; ++a) sv[a] = U[c0 + a][n];
#pragma unroll
    for (int a = 0; a < 4; ++a)
#pragma unroll
      for (int bb = 0; bb < 4; ++bb) inter[a][bb] += cv[a] * sv[bb];
  }
  __syncthreads();
  for (int r = grp; r < 64; r += 4)
    V[r][lane] = xp[(base + r) * 192 + lane];           // X
  __syncthreads();
  float Dv = Dp[dir];
  float acc[4][4];
#pragma unroll
  for (int a = 0; a < 4; ++a) {
    float et = expf(cumS[t0 + a]);
#pragma unroll
    for (int bb = 0; bb < 4; ++bb)
      acc[a][bb] = et * inter[a][bb] + Dv * V[t0 + a][c0 + bb];
  }
  for (int s = 0; s < 64; ++s) {
    float gv[4], xv[4];
#pragma unroll
    for (int a = 0; a < 4; ++a) gv[a] = G[t0 + a][s];
#pragma unroll
    for (int a = 0; a < 4; ++a) xv[a] = V[s][c0 + a];
#pragma unroll
    for (int a = 0; a < 4; ++a)
#pragma unroll
      for (int bb = 0; bb < 4; ++bb) acc[a][bb] += gv[a] * xv[bb];
  }
  // ---- fused epilogue: gate, RMSNorm, out-proj ----
  __syncthreads();             // all V/G reads done
#pragma unroll
  for (int a = 0; a < 4; ++a) {
    float4 zv = *(const float4*)&zp[(base + t0 + a) * 64 + c0];
    G[t0 + a][c0 + 0] = acc[a][0] * siluf(zv.x);
    G[t0 + a][c0 + 1] = acc[a][1] * siluf(zv.y);
    G[t0 + a][c0 + 2] = acc[a][2] * siluf(zv.z);
    G[t0 + a][c0 + 3] = acc[a][3] * siluf(zv.w);
  }
  for (int i = tid; i < 2048; i += 256) {       // Wn into V (V dead)
    int p = i >> 5, d = i & 31;
    V[p][d] = normw[dir * 64 + p] * Wout[(long)dir * 2048 + p * 32 + d];
  }
  __syncthreads();
  {
    int wv = tid >> 6, rw = tid & 63;
    float pp = 0.f;
    for (int p2 = wv * 16; p2 < wv * 16 + 16; ++p2) { float v = G[rw][p2]; pp += v * v; }
    part[wv][rw] = pp;
  }
  __syncthreads();
  if (tid < 64)
    rsc[tid] = rsqrtf((part[0][tid] + part[1][tid] + part[2][tid] + part[3][tid]) *
                          (1.0f / 64.0f) + 1e-5f);
  __syncthreads();
  int tx2 = tid & 31, ty2 = tid >> 5;
  float a8[8] = {};
  for (int p = 0; p < 64; ++p) {
    float wv = V[p][tx2];
#pragma unroll
    for (int r8 = 0; r8 < 8; ++r8) a8[r8] += G[ty2 * 8 + r8][p] * wv;
  }
  float* s2x = dir ? s2b : s2a;
#pragma unroll
  for (int r8 = 0; r8 < 8; ++r8) {
    int r = ty2 * 8 + r8;
    int l = k * 64 + r;
    int lout = dir ? (4095 - l) : l;
    s2x[((long)b * 4096 + lout) * 32 + tx2] = a8[r8] * rsc[r];
  }
}

// K10: o3 = (s2a+s2b)@W, + fused BN partial sums via atomics.
__global__ void k_fcout(const float* __restrict__ s2a, const float* __restrict__ s2b,
                        const float* __restrict__ w, float* __restrict__ o3,
                        float* __restrict__ stats) {
  __shared__ float st[32][65];
  __shared__ float wt[32][64];
  int b = blockIdx.y, l0 = blockIdx.x * 64, cb = blockIdx.z * 64;
  int tid = threadIdx.x;
  {
    int d = tid & 31, l = tid >> 5;
    for (int si = 0; si < 8; ++si) {
      int ll = l + si * 8;
      long o = ((long)b * 4096 + l0 + ll) * 32 + d;
      st[d][ll] = s2a[o] + s2b[o];
    }
    int f4 = (tid & 15) * 4, r = tid >> 4;
    for (int si = 0; si < 2; ++si) {
      int rr = r + si * 16;
      *(float4*)&wt[rr][f4] = *(const float4*)&w[rr * 128 + cb + f4];
    }
  }
  __syncthreads();
  int tx = tid & 15, ty = tid >> 4;
  int c0 = tx * 4, t0 = ty * 4;
  float acc[4][4] = {};
  for (int k = 0; k < 32; ++k) {
    float xa[4];
#pragma unroll
    for (int q = 0; q < 4; ++q) xa[q] = st[k][c0 + q];
    float4 wv = *(float4*)&wt[k][t0];
    float wa[4] = {wv.x, wv.y, wv.z, wv.w};
#pragma unroll
    for (int a = 0; a < 4; ++a)
#pragma unroll
      for (int q = 0; q < 4; ++q) acc[a][q] += wa[a] * xa[q];
  }
#pragma unroll
  for (int a = 0; a < 4; ++a)
    *(float4*)&o3[((long)b * 128 + cb + t0 + a) * 4096 + l0 + c0] =
        make_float4(acc[a][0], acc[a][1], acc[a][2], acc[a][3]);
#pragma unroll
  for (int a = 0; a < 4; ++a) {
    float ps = acc[a][0] + acc[a][1] + acc[a][2] + acc[a][3];
    float pq = acc[a][0] * acc[a][0] + acc[a][1] * acc[a][1] +
               acc[a][2] * acc[a][2] + acc[a][3] * acc[a][3];
#pragma unroll
    for (int off = 8; off >= 1; off >>= 1) {
      ps += __shfl_down(ps, off);
      pq += __shfl_down(pq, off);
    }
    if (tx == 0) {
      atomicAdd(&stats[cb + t0 + a], ps);
      atomicAdd(&stats[128 + cb + t0 + a], pq);
    }
  }
}

// K12: BN + conv4 (128->128) + sigmoid + gated residual. 4x4 micro-tiles.
__global__ void k_final(const float* __restrict__ o3, const float* __restrict__ stats,
                        const float* __restrict__ bng, const float* __restrict__ bnb,
                        const float* __restrict__ w, const float* __restrict__ bias,
                        const float* __restrict__ x, float* __restrict__ out) {
  __shared__ float xt[128][64];
  __shared__ float wt[128][64];
  __shared__ float sc[128], sh[128];
  int b = blockIdx.y, l0 = blockIdx.x * 64, cb = blockIdx.z * 64;
  int tid = threadIdx.x;
  if (tid < 128) {
    float mu = stats[tid] * (1.0f / 32768.0f);
    float var = stats[128 + tid] * (1.0f / 32768.0f) - mu * mu;
    float r = rsqrtf(var + 1e-5f);
    sc[tid] = r * bng[tid];
    sh[tid] = bnb[tid] - mu * r * bng[tid];
  }
  __syncthreads();
  int f4 = (tid & 15) * 4, r0 = tid >> 4;
#pragma unroll
  for (int s = 0; s < 8; ++s) {
    int r = r0 + s * 16;
    float4 v = *(const float4*)&o3[((long)b * 128 + r) * 4096 + l0 + f4];
    float scr = sc[r], shr = sh[r];
    *(float4*)&xt[r][f4] = make_float4(fmaf(v.x, scr, shr), fmaf(v.y, scr, shr),
                                       fmaf(v.z, scr, shr), fmaf(v.w, scr, shr));
    *(float4*)&wt[r][f4] = *(const float4*)&w[r * 128 + cb + f4];
  }
  __syncthreads();
  int tx = tid & 15, ty = tid >> 4;
  int c0 = tx * 4, t0 = ty * 4;
  float acc[4][4];
#pragma unroll
  for (int a = 0; a < 4; ++a) {
    float bv = bias[cb + t0 + a];
#pragma unroll
    for (int q = 0; q < 4; ++q) acc[a][q] = bv;
  }
  for (int k = 0; k < 128; ++k) {
    float4 xv = *(float4*)&xt[k][c0];
    float4 wv = *(float4*)&wt[k][t0];
    float xa[4] = {xv.x, xv.y, xv.z, xv.w};
    float wa[4] = {wv.x, wv.y, wv.z, wv.w};
#pragma unroll
    for (int a = 0; a < 4; ++a)
#pragma unroll
      for (int q = 0; q < 4; ++q) acc[a][q] += wa[a] * xa[q];
  }
#pragma unroll
  for (int a = 0; a < 4; ++a) {
    long xi = ((long)b * 128 + cb + t0 + a) * 4096 + l0 + c0;
    float4 xv = *(const float4*)&x[xi];
    float4 o4;
    o4.x = xv.x * (1.0f + 1.0f / (1.0f + expf(-acc[a][0])));
    o4.y = xv.y * (1.0f + 1.0f / (1.0f + expf(-acc[a][1])));
    o4.z = xv.z * (1.0f + 1.0f / (1.0f + expf(-acc[a][2])));
    o4.w = xv.w * (1.0f + 1.0f / (1.0f + expf(-acc[a][3])));
    *(float4*)&out[xi] = o4;
  }
}

extern "C" void kernel_launch(void* const* d_in, const int* in_sizes, int n_in,
                              void* d_out, int out_size, void* d_ws, size_t ws_size,
                              hipStream_t stream) {
  const float* x          = (const float*)d_in[0];
  const float* lin1_w     = (const float*)d_in[1];
  const float* lin1_b     = (const float*)d_in[2];
  const float* dw_w       = (const float*)d_in[3];
  const float* dw_b       = (const float*)d_in[4];
  const float* fc_in_w    = (const float*)d_in[5];
  const float* mam_in_w   = (const float*)d_in[6];
  const float* mam_conv_w = (const float*)d_in[7];
  const float* mam_conv_b = (const float*)d_in[8];
  const float* mam_dt_bias= (const float*)d_in[9];
  const float* mam_A_log  = (const float*)d_in[10];
  const float* mam_D      = (const float*)d_in[11];
  const float* mam_norm_w = (const float*)d_in[12];
  const float* mam_out_w  = (const float*)d_in[13];
  const float* fc_out_w   = (const float*)d_in[14];
  const float* bn_g       = (const float*)d_in[15];
  const float* bn_b       = (const float*)d_in[16];
  const float* conv4_w    = (const float*)d_in[17];
  const float* conv4_b    = (const float*)d_in[18];
  float* out = (float*)d_out;
  float* ws  = (float*)d_ws;

  float* o1   = ws + OFF_O1;
  float* o2   = ws + OFF_O2;
  float* sbuf = ws + OFF_S;
  float* zbuf = ws + OFF_Z;
  float* xbca = ws + OFF_XBCA;
  float* dts  = ws + OFF_DTS;
  float* cum  = ws + OFF_CUM;
  float* Tbuf = ws + OFF_T;
  float* Sprev= ws + OFF_SPREV;
  float* s2a  = ws + OFF_S2A;
  float* s2b  = ws + OFF_S2B;
  float* bnst = ws + OFF_BN;
  float* o3   = ws + OFF_O3;

  hipMemsetAsync(bnst, 0, 256 * sizeof(float), stream);

  k_lin1<<<dim3(64, 8, 2), 256, 0, stream>>>(x, lin1_w, lin1_b, o1);
  k_dw<<<1024, 256, 0, stream>>>(o1, dw_w, dw_b, o2);
  k_fcin<<<dim3(64, 8), 256, 0, stream>>>(o2, fc_in_w, sbuf);
  k_inprojconv<<<dim3(64, 8, 2), 256, 0, stream>>>(sbuf, mam_in_w, mam_conv_w, mam_conv_b,
                                                   mam_dt_bias, mam_A_log,
                                                   zbuf, xbca, dts, cum);
  k_chunkT<<<dim3(512, 2), 256, 0, stream>>>(xbca, dts, cum, Tbuf);
  k_scan<<<256, 256, 0, stream>>>(Tbuf, cum, Sprev);
  k_chunkYout<<<dim3(512, 2), 256, 0, stream>>>(xbca, dts, cum, Sprev, mam_D, zbuf,
                                                mam_norm_w, mam_out_w, s2a, s2b);
  k_fcout<<<dim3(64, 8, 2), 256, 0, stream>>>(s2a, s2b, fc_out_w, o3, bnst);
  k_final<<<dim3(64, 8, 2), 256, 0, stream>>>(o3, bnst, bn_g, bn_b, conv4_w, conv4_b, x, out);
}

// Round 6
// 334.473 us; speedup vs baseline: 5.1297x; 1.1763x over previous
//
#include <hip/hip_runtime.h>
#include <math.h>

// Problem constants
constexpr int Bn = 8, Cn = 128, Ln = 4096;

// Workspace layout (float offsets).
constexpr size_t OFF_O1   = 0;          // o1; later o3 (aliased)
constexpr size_t OFF_O2   = 4194304;
constexpr size_t OFF_S    = 8388608;
constexpr size_t OFF_Z    = 9437184;    // 2 dirs x 2,097,152
constexpr size_t OFF_XBCA = 13631488;   // 2 dirs x 6,291,456
constexpr size_t OFF_DTS  = 26214400;
constexpr size_t OFF_CUM  = 26279936;
constexpr size_t OFF_T    = 26345472;   // 2 dirs x 2,097,152
constexpr size_t OFF_SPREV= 30539776;   // 2 dirs x 2,097,152
constexpr size_t OFF_S2A  = 34734080;
constexpr size_t OFF_S2B  = 35782656;
constexpr size_t OFF_BN   = 36831232;
constexpr size_t OFF_O3   = 0;

constexpr long ZSTRIDE = 2097152;
constexpr long XSTRIDE = 6291456;
constexpr long TSTRIDE = 2097152;

__device__ __forceinline__ float siluf(float v) { return v / (1.0f + expf(-v)); }

// K1: o1[b,o,l] = sum_i x[b,i,l]*w[i,o] + bias[o]. 4x4 micro-tiles, 64Lx64C.
__global__ void k_lin1(const float* __restrict__ x, const float* __restrict__ w,
                       const float* __restrict__ bias, float* __restrict__ o1) {
  __shared__ float xt[128][64];
  __shared__ float wt[128][64];
  int b = blockIdx.y, l0 = blockIdx.x * 64, cb = blockIdx.z * 64;
  int tid = threadIdx.x;
  int f4 = (tid & 15) * 4, r0 = tid >> 4;
#pragma unroll
  for (int s = 0; s < 8; ++s) {
    int r = r0 + s * 16;
    *(float4*)&xt[r][f4] = *(const float4*)&x[((long)b * 128 + r) * 4096 + l0 + f4];
    *(float4*)&wt[r][f4] = *(const float4*)&w[r * 128 + cb + f4];
  }
  __syncthreads();
  int tx = tid & 15, ty = tid >> 4;
  int c0 = tx * 4, t0 = ty * 4;
  float acc[4][4];
#pragma unroll
  for (int a = 0; a < 4; ++a) {
    float bv = bias[cb + t0 + a];
#pragma unroll
    for (int q = 0; q < 4; ++q) acc[a][q] = bv;
  }
  for (int k = 0; k < 128; ++k) {
    float4 xv = *(float4*)&xt[k][c0];
    float4 wv = *(float4*)&wt[k][t0];
    float xa[4] = {xv.x, xv.y, xv.z, xv.w};
    float wa[4] = {wv.x, wv.y, wv.z, wv.w};
#pragma unroll
    for (int a = 0; a < 4; ++a)
#pragma unroll
      for (int q = 0; q < 4; ++q) acc[a][q] += wa[a] * xa[q];
  }
#pragma unroll
  for (int a = 0; a < 4; ++a)
    *(float4*)&o1[((long)b * 128 + cb + t0 + a) * 4096 + l0 + c0] =
        make_float4(acc[a][0], acc[a][1], acc[a][2], acc[a][3]);
}

// K2: depthwise 3x3 SAME + bias + silu. 4x4 patch per thread from LDS plane.
__global__ void k_dw(const float* __restrict__ o1, const float* __restrict__ wgt,
                     const float* __restrict__ bias, float* __restrict__ o2) {
  __shared__ float p[4096];
  int bc = blockIdx.x, c = bc & 127, tid = threadIdx.x;
  const float* src = o1 + (long)bc * 4096;
#pragma unroll
  for (int s4 = 0; s4 < 4; ++s4) {
    int off = s4 * 1024 + tid * 4;
    *(float4*)&p[off] = *(const float4*)&src[off];
  }
  float wr[9];
#pragma unroll
  for (int j = 0; j < 9; ++j) wr[j] = wgt[c * 9 + j];
  float bv = bias[c];
  __syncthreads();
  int wg = tid & 15, hs = tid >> 4;
  int w0 = wg * 4, h0 = hs * 4;
  float in[6][6];
#pragma unroll
  for (int ri = 0; ri < 6; ++ri) {
    int h = h0 - 1 + ri;
    if (h < 0 || h > 63) {
#pragma unroll
      for (int ci = 0; ci < 6; ++ci) in[ri][ci] = 0.f;
    } else {
      float4 cc = *(float4*)&p[h * 64 + w0];
      in[ri][1] = cc.x; in[ri][2] = cc.y; in[ri][3] = cc.z; in[ri][4] = cc.w;
      in[ri][0] = (w0 > 0) ? p[h * 64 + w0 - 1] : 0.f;
      in[ri][5] = (w0 < 60) ? p[h * 64 + w0 + 4] : 0.f;
    }
  }
#pragma unroll
  for (int r = 0; r < 4; ++r) {
    float oc[4];
#pragma unroll
    for (int q = 0; q < 4; ++q) {
      float acc = bv;
#pragma unroll
      for (int dh = 0; dh < 3; ++dh)
#pragma unroll
        for (int dq = 0; dq < 3; ++dq)
          acc += in[r + dh][q + dq] * wr[dh * 3 + dq];
      oc[q] = siluf(acc);
    }
    *(float4*)&o2[(long)bc * 4096 + (h0 + r) * 64 + w0] =
        make_float4(oc[0], oc[1], oc[2], oc[3]);
  }
}

// K3: s[b,l,d] = sum_c o2[b,c,l]*w[c,d]  (d<32). 4x2 micro-tiles.
__global__ void k_fcin(const float* __restrict__ o2, const float* __restrict__ w,
                       float* __restrict__ s) {
  __shared__ float xt[128][64];
  __shared__ float wt[128][32];
  int b = blockIdx.y, l0 = blockIdx.x * 64;
  int tid = threadIdx.x;
  int f4 = (tid & 15) * 4, r0 = tid >> 4;
#pragma unroll
  for (int st = 0; st < 8; ++st) {
    int r = r0 + st * 16;
    *(float4*)&xt[r][f4] = *(const float4*)&o2[((long)b * 128 + r) * 4096 + l0 + f4];
  }
  int f4w = (tid & 7) * 4, rw = tid >> 3;
#pragma unroll
  for (int st = 0; st < 4; ++st) {
    int r = rw + st * 32;
    *(float4*)&wt[r][f4w] = *(const float4*)&w[r * 32 + f4w];
  }
  __syncthreads();
  int tx = tid & 15, ty = tid >> 4;
  int c0 = tx * 4, d0 = ty * 2;
  float acc[2][4] = {};
  for (int k = 0; k < 128; ++k) {
    float4 xv = *(float4*)&xt[k][c0];
    float2 wv = *(float2*)&wt[k][d0];
    float xa[4] = {xv.x, xv.y, xv.z, xv.w};
#pragma unroll
    for (int q = 0; q < 4; ++q) {
      acc[0][q] += wv.x * xa[q];
      acc[1][q] += wv.y * xa[q];
    }
  }
#pragma unroll
  for (int q = 0; q < 4; ++q) {
    long ob = ((long)b * 4096 + l0 + c0 + q) * 32 + d0;
    *(float2*)&s[ob] = make_float2(acc[0][q], acc[1][q]);
  }
}

// K4: in_proj + causal conv1d + silu + dt softplus + cum, both dirs, fused.
__global__ void k_inprojconv(const float* __restrict__ s, const float* __restrict__ Win,
                             const float* __restrict__ conv_w, const float* __restrict__ conv_b,
                             const float* __restrict__ dt_bias, const float* __restrict__ A_log,
                             float* __restrict__ z, float* __restrict__ xbca,
                             float* __restrict__ dts, float* __restrict__ cum) {
  __shared__ float st[67][36];
  __shared__ float xbcL[67][192];
  __shared__ float wT[4][192];
  __shared__ float bcv[192];
  int dir = blockIdx.z;
  int b = blockIdx.y, l0 = blockIdx.x * 64;
  int tid = threadIdx.x;
  if (tid < 192) {
    bcv[tid] = conv_b[dir * 192 + tid];
#pragma unroll
    for (int j = 0; j < 4; ++j) wT[j][tid] = conv_w[dir * 768 + tid * 4 + j];
  }
  for (int i = tid; i < 67 * 32; i += 256) {
    int rr = i >> 5, k2 = i & 31;
    int l = l0 - 3 + rr;
    float v = 0.f;
    if (l >= 0) {
      int lsrc = dir ? (4095 - l) : l;
      v = s[((long)b * 4096 + lsrc) * 32 + k2];
    }
    st[rr][k2] = v;
  }
  __syncthreads();
  const float* W = Win + (long)dir * 32 * 257;
  float wreg[32];
#pragma unroll
  for (int k2 = 0; k2 < 32; ++k2) wreg[k2] = W[k2 * 257 + tid];
  long rowbase = (long)b * 4096 + l0;
  if (tid < 64) {
    float* zp = z + (long)dir * ZSTRIDE;
    for (int r = 0; r < 64; ++r) {
      float a = 0.f;
#pragma unroll
      for (int k2 = 0; k2 < 32; k2 += 4) {
        float4 sv = *(float4*)&st[r + 3][k2];
        a += sv.x * wreg[k2] + sv.y * wreg[k2 + 1] + sv.z * wreg[k2 + 2] + sv.w * wreg[k2 + 3];
      }
      zp[(rowbase + r) * 64 + tid] = a;
    }
    float a = 0.f;
#pragma unroll
    for (int k2 = 0; k2 < 32; ++k2) a += st[tid + 3][k2] * W[k2 * 257 + 256];
    float v = a + dt_bias[dir];
    float sp = (v > 20.f) ? v : log1pf(expf(v));
    dts[dir * 32768 + rowbase + tid] = sp;
    float cd = -expf(A_log[dir]) * sp;
#pragma unroll
    for (int off = 1; off < 64; off <<= 1) {
      float u = __shfl_up(cd, off);
      if (tid >= off) cd += u;
    }
    cum[dir * 32768 + rowbase + tid] = cd;
  } else {
    int c = tid - 64;
    for (int r = 0; r < 67; ++r) {
      float a = 0.f;
#pragma unroll
      for (int k2 = 0; k2 < 32; k2 += 4) {
        float4 sv = *(float4*)&st[r][k2];
        a += sv.x * wreg[k2] + sv.y * wreg[k2 + 1] + sv.z * wreg[k2 + 2] + sv.w * wreg[k2 + 3];
      }
      xbcL[r][c] = a;
    }
  }
  __syncthreads();
  float* xp = xbca + (long)dir * XSTRIDE;
  for (int i = tid; i < 64 * 48; i += 256) {
    int r = i / 48, cq = (i - r * 48) * 4;
    float4 acc4 = *(float4*)&bcv[cq];
#pragma unroll
    for (int j = 0; j < 4; ++j) {
      float4 xv = *(float4*)&xbcL[r + j][cq];
      float4 wv = *(float4*)&wT[j][cq];
      acc4.x += xv.x * wv.x; acc4.y += xv.y * wv.y;
      acc4.z += xv.z * wv.z; acc4.w += xv.w * wv.w;
    }
    *(float4*)&xp[(rowbase + r) * 192 + cq] =
        make_float4(siluf(acc4.x), siluf(acc4.y), siluf(acc4.z), siluf(acc4.w));
  }
}

// K6: chunk summary T[p][n] = sum_s f_s*X_s[p]*B_s[n].
// [68] row padding => 16B-aligned rows => real ds_read_b128.
__global__ void k_chunkT(const float* __restrict__ xbca, const float* __restrict__ dts,
                         const float* __restrict__ cum, float* __restrict__ T) {
  __shared__ float Xs[64][68], Bs[64][68];
  int dir = blockIdx.y;
  int bk = blockIdx.x, b = bk >> 6, k = bk & 63;
  int tid = threadIdx.x, lane = tid & 63, grp = tid >> 6;
  const float* xp = xbca + (long)dir * XSTRIDE;
  const float* dtp = dts + dir * 32768;
  const float* cp = cum + dir * 32768;
  long base = (long)b * 4096 + (long)k * 64;
  float clend = cp[base + 63];
  for (int r = grp; r < 64; r += 4) {
    float f = expf(clend - cp[base + r]) * dtp[base + r];
    Xs[r][lane] = xp[(base + r) * 192 + lane] * f;
    Bs[r][lane] = xp[(base + r) * 192 + 64 + lane];
  }
  __syncthreads();
  int tx = tid & 15, ty = tid >> 4;
  int p0 = ty * 4, n0 = tx * 4;
  float acc[4][4] = {};
  for (int s = 0; s < 64; ++s) {
    float4 xv = *(float4*)&Xs[s][p0];
    float4 bv = *(float4*)&Bs[s][n0];
    float xa[4] = {xv.x, xv.y, xv.z, xv.w};
    float ba[4] = {bv.x, bv.y, bv.z, bv.w};
#pragma unroll
    for (int a = 0; a < 4; ++a)
#pragma unroll
      for (int q = 0; q < 4; ++q) acc[a][q] += xa[a] * ba[q];
  }
#pragma unroll
  for (int a = 0; a < 4; ++a)
    *(float4*)&T[(long)dir * TSTRIDE + (long)bk * 4096 + (p0 + a) * 64 + n0] =
        make_float4(acc[a][0], acc[a][1], acc[a][2], acc[a][3]);
}

// K7: inter-chunk state scan (both dirs)
__global__ void k_scan(const float* __restrict__ T, const float* __restrict__ cum,
                       float* __restrict__ Sprev) {
  int idx = blockIdx.x * 256 + threadIdx.x;   // 65536
  int dir = idx >> 15, rem = idx & 32767;
  int b = rem >> 12, pn = rem & 4095;
  const float* Tp = T + (long)dir * TSTRIDE;
  float* Sp = Sprev + (long)dir * TSTRIDE;
  const float* cp = cum + dir * 32768 + b * 4096;
  float sacc = 0.f;
  for (int k = 0; k < 64; ++k) {
    long o = ((long)(b * 64 + k)) * 4096 + pn;
    Sp[o] = sacc;
    sacc = expf(cp[k * 64 + 63]) * sacc + Tp[o];
  }
}

// K8: per-chunk Y + gate + RMSNorm + out-proj, fully fused.
__global__ void k_chunkYout(const float* __restrict__ xbca, const float* __restrict__ dts,
                            const float* __restrict__ cum, const float* __restrict__ Sprev,
                            const float* __restrict__ Dp, const float* __restrict__ z,
                            const float* __restrict__ normw, const float* __restrict__ Wout,
                            float* __restrict__ s2a, float* __restrict__ s2b) {
  __shared__ float U[64][65];
  __shared__ float V[64][65];
  __shared__ float G[64][65];
  __shared__ float cumS[64];
  __shared__ float part[4][64];
  __shared__ float rsc[64];
  int dir = blockIdx.y;
  int bk = blockIdx.x, b = bk >> 6, k = bk & 63;
  int tid = threadIdx.x, lane = tid & 63, grp = tid >> 6;
  const float* xp = xbca + (long)dir * XSTRIDE;
  const float* dtp = dts + dir * 32768;
  const float* cp = cum + dir * 32768;
  const float* Sp = Sprev + (long)dir * TSTRIDE;
  const float* zp = z + (long)dir * ZSTRIDE;
  long base = (long)b * 4096 + (long)k * 64;
  for (int r = grp; r < 64; r += 4) {
    float dtv = dtp[base + r];
    U[r][lane] = xp[(base + r) * 192 + 64 + lane] * dtv;
    V[r][lane] = xp[(base + r) * 192 + 128 + lane];
  }
  if (tid < 64) cumS[tid] = cp[base + tid];
  __syncthreads();
  int tx = tid & 15, ty = tid >> 4;
  int t0 = ty * 4, c0 = tx * 4;
  {
    float g[4][4] = {};
    for (int i = 0; i < 64; ++i) {
      float cv[4], uv[4];
#pragma unroll
      for (int a = 0; a < 4; ++a) cv[a] = V[t0 + a][i];
#pragma unroll
      for (int a = 0; a < 4; ++a) uv[a] = U[c0 + a][i];
#pragma unroll
      for (int a = 0; a < 4; ++a)
#pragma unroll
        for (int bb = 0; bb < 4; ++bb) g[a][bb] += cv[a] * uv[bb];
    }
#pragma unroll
    for (int a = 0; a < 4; ++a) {
      float ct = cumS[t0 + a];
#pragma unroll
      for (int bb = 0; bb < 4; ++bb) {
        int l = c0 + bb;
        G[t0 + a][l] = (l <= t0 + a) ? g[a][bb] * expf(ct - cumS[l]) : 0.f;
      }
    }
  }
  __syncthreads();
  for (int r = grp; r < 64; r += 4)
    U[r][lane] = Sp[(long)bk * 4096 + r * 64 + lane];
  __syncthreads();
  float inter[4][4] = {};
  for (int n = 0; n < 64; ++n) {
    float cv[4], sv[4];
#pragma unroll
    for (int a = 0; a < 4; ++a) cv[a] = V[t0 + a][n];
#pragma unroll
    for (int a = 0; a < 4; ++a) sv[a] = U[c0 + a][n];
#pragma unroll
    for (int a = 0; a < 4; ++a)
#pragma unroll
      for (int bb = 0; bb < 4; ++bb) inter[a][bb] += cv[a] * sv[bb];
  }
  __syncthreads();
  for (int r = grp; r < 64; r += 4)
    V[r][lane] = xp[(base + r) * 192 + lane];
  __syncthreads();
  float Dv = Dp[dir];
  float acc[4][4];
#pragma unroll
  for (int a = 0; a < 4; ++a) {
    float et = expf(cumS[t0 + a]);
#pragma unroll
    for (int bb = 0; bb < 4; ++bb)
      acc[a][bb] = et * inter[a][bb] + Dv * V[t0 + a][c0 + bb];
  }
  for (int s = 0; s < 64; ++s) {
    float gv[4], xv[4];
#pragma unroll
    for (int a = 0; a < 4; ++a) gv[a] = G[t0 + a][s];
#pragma unroll
    for (int a = 0; a < 4; ++a) xv[a] = V[s][c0 + a];
#pragma unroll
    for (int a = 0; a < 4; ++a)
#pragma unroll
      for (int bb = 0; bb < 4; ++bb) acc[a][bb] += gv[a] * xv[bb];
  }
  __syncthreads();
#pragma unroll
  for (int a = 0; a < 4; ++a) {
    float4 zv = *(const float4*)&zp[(base + t0 + a) * 64 + c0];
    G[t0 + a][c0 + 0] = acc[a][0] * siluf(zv.x);
    G[t0 + a][c0 + 1] = acc[a][1] * siluf(zv.y);
    G[t0 + a][c0 + 2] = acc[a][2] * siluf(zv.z);
    G[t0 + a][c0 + 3] = acc[a][3] * siluf(zv.w);
  }
  for (int i = tid; i < 2048; i += 256) {
    int p = i >> 5, d = i & 31;
    V[p][d] = normw[dir * 64 + p] * Wout[(long)dir * 2048 + p * 32 + d];
  }
  __syncthreads();
  {
    int wv = tid >> 6, rw = tid & 63;
    float pp = 0.f;
    for (int p2 = wv * 16; p2 < wv * 16 + 16; ++p2) { float v = G[rw][p2]; pp += v * v; }
    part[wv][rw] = pp;
  }
  __syncthreads();
  if (tid < 64)
    rsc[tid] = rsqrtf((part[0][tid] + part[1][tid] + part[2][tid] + part[3][tid]) *
                          (1.0f / 64.0f) + 1e-5f);
  __syncthreads();
  int tx2 = tid & 31, ty2 = tid >> 5;
  float a8[8] = {};
  for (int p = 0; p < 64; ++p) {
    float wv = V[p][tx2];
#pragma unroll
    for (int r8 = 0; r8 < 8; ++r8) a8[r8] += G[ty2 * 8 + r8][p] * wv;
  }
  float* s2x = dir ? s2b : s2a;
#pragma unroll
  for (int r8 = 0; r8 < 8; ++r8) {
    int r = ty2 * 8 + r8;
    int l = k * 64 + r;
    int lout = dir ? (4095 - l) : l;
    s2x[((long)b * 4096 + lout) * 32 + tx2] = a8[r8] * rsc[r];
  }
}

// K10: o3 = (s2a+s2b)@W — pure GEMM (atomics de-fused; they cost 66us in r5).
__global__ void k_fcout(const float* __restrict__ s2a, const float* __restrict__ s2b,
                        const float* __restrict__ w, float* __restrict__ o3) {
  __shared__ float st[32][68];
  __shared__ float wt[32][64];
  int b = blockIdx.y, l0 = blockIdx.x * 64, cb = blockIdx.z * 64;
  int tid = threadIdx.x;
  {
    int d = tid & 31, l = tid >> 5;
    for (int si = 0; si < 8; ++si) {
      int ll = l + si * 8;
      long o = ((long)b * 4096 + l0 + ll) * 32 + d;
      st[d][ll] = s2a[o] + s2b[o];
    }
    int f4 = (tid & 15) * 4, r = tid >> 4;
    for (int si = 0; si < 2; ++si) {
      int rr = r + si * 16;
      *(float4*)&wt[rr][f4] = *(const float4*)&w[rr * 128 + cb + f4];
    }
  }
  __syncthreads();
  int tx = tid & 15, ty = tid >> 4;
  int c0 = tx * 4, t0 = ty * 4;
  float acc[4][4] = {};
  for (int k = 0; k < 32; ++k) {
    float4 xv = *(float4*)&st[k][c0];
    float4 wv = *(float4*)&wt[k][t0];
    float xa[4] = {xv.x, xv.y, xv.z, xv.w};
    float wa[4] = {wv.x, wv.y, wv.z, wv.w};
#pragma unroll
    for (int a = 0; a < 4; ++a)
#pragma unroll
      for (int q = 0; q < 4; ++q) acc[a][q] += wa[a] * xa[q];
  }
#pragma unroll
  for (int a = 0; a < 4; ++a)
    *(float4*)&o3[((long)b * 128 + cb + t0 + a) * 4096 + l0 + c0] =
        make_float4(acc[a][0], acc[a][1], acc[a][2], acc[a][3]);
}

// K10b: per-channel sums for BatchNorm (2 atomics per block — no contention)
__global__ void k_bnstat(const float* __restrict__ o3, float* __restrict__ stats) {
  int bc = blockIdx.x;  // 1024 = (b,c)
  int tid = threadIdx.x;
  const float* p = o3 + (long)bc * 4096;
  float s = 0.f, q = 0.f;
  for (int i = tid * 4; i < 4096; i += 1024) {
    float4 v = *(const float4*)&p[i];
    s += v.x + v.y + v.z + v.w;
    q += v.x * v.x + v.y * v.y + v.z * v.z + v.w * v.w;
  }
  __shared__ float rs[4], rq[4];
  for (int off = 32; off; off >>= 1) { s += __shfl_down(s, off); q += __shfl_down(q, off); }
  if ((tid & 63) == 0) { rs[tid >> 6] = s; rq[tid >> 6] = q; }
  __syncthreads();
  if (tid == 0) {
    float a = rs[0] + rs[1] + rs[2] + rs[3];
    float b2 = rq[0] + rq[1] + rq[2] + rq[3];
    int c = bc & 127;
    atomicAdd(&stats[c], a);
    atomicAdd(&stats[128 + c], b2);
  }
}

// K12: BN + conv4 (128->128) + sigmoid + gated residual. 4x4 micro-tiles.
__global__ void k_final(const float* __restrict__ o3, const float* __restrict__ stats,
                        const float* __restrict__ bng, const float* __restrict__ bnb,
                        const float* __restrict__ w, const float* __restrict__ bias,
                        const float* __restrict__ x, float* __restrict__ out) {
  __shared__ float xt[128][64];
  __shared__ float wt[128][64];
  __shared__ float sc[128], sh[128];
  int b = blockIdx.y, l0 = blockIdx.x * 64, cb = blockIdx.z * 64;
  int tid = threadIdx.x;
  if (tid < 128) {
    float mu = stats[tid] * (1.0f / 32768.0f);
    float var = stats[128 + tid] * (1.0f / 32768.0f) - mu * mu;
    float r = rsqrtf(var + 1e-5f);
    sc[tid] = r * bng[tid];
    sh[tid] = bnb[tid] - mu * r * bng[tid];
  }
  __syncthreads();
  int f4 = (tid & 15) * 4, r0 = tid >> 4;
#pragma unroll
  for (int s = 0; s < 8; ++s) {
    int r = r0 + s * 16;
    float4 v = *(const float4*)&o3[((long)b * 128 + r) * 4096 + l0 + f4];
    float scr = sc[r], shr = sh[r];
    *(float4*)&xt[r][f4] = make_float4(fmaf(v.x, scr, shr), fmaf(v.y, scr, shr),
                                       fmaf(v.z, scr, shr), fmaf(v.w, scr, shr));
    *(float4*)&wt[r][f4] = *(const float4*)&w[r * 128 + cb + f4];
  }
  __syncthreads();
  int tx = tid & 15, ty = tid >> 4;
  int c0 = tx * 4, t0 = ty * 4;
  float acc[4][4];
#pragma unroll
  for (int a = 0; a < 4; ++a) {
    float bv = bias[cb + t0 + a];
#pragma unroll
    for (int q = 0; q < 4; ++q) acc[a][q] = bv;
  }
  for (int k = 0; k < 128; ++k) {
    float4 xv = *(float4*)&xt[k][c0];
    float4 wv = *(float4*)&wt[k][t0];
    float xa[4] = {xv.x, xv.y, xv.z, xv.w};
    float wa[4] = {wv.x, wv.y, wv.z, wv.w};
#pragma unroll
    for (int a = 0; a < 4; ++a)
#pragma unroll
      for (int q = 0; q < 4; ++q) acc[a][q] += wa[a] * xa[q];
  }
#pragma unroll
  for (int a = 0; a < 4; ++a) {
    long xi = ((long)b * 128 + cb + t0 + a) * 4096 + l0 + c0;
    float4 xv = *(const float4*)&x[xi];
    float4 o4;
    o4.x = xv.x * (1.0f + 1.0f / (1.0f + expf(-acc[a][0])));
    o4.y = xv.y * (1.0f + 1.0f / (1.0f + expf(-acc[a][1])));
    o4.z = xv.z * (1.0f + 1.0f / (1.0f + expf(-acc[a][2])));
    o4.w = xv.w * (1.0f + 1.0f / (1.0f + expf(-acc[a][3])));
    *(float4*)&out[xi] = o4;
  }
}

extern "C" void kernel_launch(void* const* d_in, const int* in_sizes, int n_in,
                              void* d_out, int out_size, void* d_ws, size_t ws_size,
                              hipStream_t stream) {
  const float* x          = (const float*)d_in[0];
  const float* lin1_w     = (const float*)d_in[1];
  const float* lin1_b     = (const float*)d_in[2];
  const float* dw_w       = (const float*)d_in[3];
  const float* dw_b       = (const float*)d_in[4];
  const float* fc_in_w    = (const float*)d_in[5];
  const float* mam_in_w   = (const float*)d_in[6];
  const float* mam_conv_w = (const float*)d_in[7];
  const float* mam_conv_b = (const float*)d_in[8];
  const float* mam_dt_bias= (const float*)d_in[9];
  const float* mam_A_log  = (const float*)d_in[10];
  const float* mam_D      = (const float*)d_in[11];
  const float* mam_norm_w = (const float*)d_in[12];
  const float* mam_out_w  = (const float*)d_in[13];
  const float* fc_out_w   = (const float*)d_in[14];
  const float* bn_g       = (const float*)d_in[15];
  const float* bn_b       = (const float*)d_in[16];
  const float* conv4_w    = (const float*)d_in[17];
  const float* conv4_b    = (const float*)d_in[18];
  float* out = (float*)d_out;
  float* ws  = (float*)d_ws;

  float* o1   = ws + OFF_O1;
  float* o2   = ws + OFF_O2;
  float* sbuf = ws + OFF_S;
  float* zbuf = ws + OFF_Z;
  float* xbca = ws + OFF_XBCA;
  float* dts  = ws + OFF_DTS;
  float* cum  = ws + OFF_CUM;
  float* Tbuf = ws + OFF_T;
  float* Sprev= ws + OFF_SPREV;
  float* s2a  = ws + OFF_S2A;
  float* s2b  = ws + OFF_S2B;
  float* bnst = ws + OFF_BN;
  float* o3   = ws + OFF_O3;

  hipMemsetAsync(bnst, 0, 256 * sizeof(float), stream);

  k_lin1<<<dim3(64, 8, 2), 256, 0, stream>>>(x, lin1_w, lin1_b, o1);
  k_dw<<<1024, 256, 0, stream>>>(o1, dw_w, dw_b, o2);
  k_fcin<<<dim3(64, 8), 256, 0, stream>>>(o2, fc_in_w, sbuf);
  k_inprojconv<<<dim3(64, 8, 2), 256, 0, stream>>>(sbuf, mam_in_w, mam_conv_w, mam_conv_b,
                                                   mam_dt_bias, mam_A_log,
                                                   zbuf, xbca, dts, cum);
  k_chunkT<<<dim3(512, 2), 256, 0, stream>>>(xbca, dts, cum, Tbuf);
  k_scan<<<256, 256, 0, stream>>>(Tbuf, cum, Sprev);
  k_chunkYout<<<dim3(512, 2), 256, 0, stream>>>(xbca, dts, cum, Sprev, mam_D, zbuf,
                                                mam_norm_w, mam_out_w, s2a, s2b);
  k_fcout<<<dim3(64, 8, 2), 256, 0, stream>>>(s2a, s2b, fc_out_w, o3);
  k_bnstat<<<1024, 256, 0, stream>>>(o3, bnst);
  k_final<<<dim3(64, 8, 2), 256, 0, stream>>>(o3, bnst, bn_g, bn_b, conv4_w, conv4_b, x, out);
}

// Round 7
// 313.304 us; speedup vs baseline: 5.4764x; 1.0676x over previous
//
#include <hip/hip_runtime.h>
#include <math.h>

// Problem constants
constexpr int Bn = 8, Cn = 128, Ln = 4096;

// Workspace layout (float offsets).
constexpr size_t OFF_O1   = 0;          // o1; later o3 (aliased)
constexpr size_t OFF_O2   = 4194304;
constexpr size_t OFF_S    = 8388608;
constexpr size_t OFF_Z    = 9437184;    // 2 dirs x 2,097,152
constexpr size_t OFF_XBCA = 13631488;   // 2 dirs x 6,291,456
constexpr size_t OFF_DTS  = 26214400;
constexpr size_t OFF_CUM  = 26279936;
constexpr size_t OFF_T    = 26345472;   // 2 dirs x 2,097,152
constexpr size_t OFF_SPREV= 30539776;   // 2 dirs x 2,097,152
constexpr size_t OFF_S2A  = 34734080;
constexpr size_t OFF_S2B  = 35782656;
constexpr size_t OFF_BN   = 36831232;
constexpr size_t OFF_O3   = 0;

constexpr long ZSTRIDE = 2097152;
constexpr long XSTRIDE = 6291456;
constexpr long TSTRIDE = 2097152;

__device__ __forceinline__ float siluf(float v) { return v / (1.0f + expf(-v)); }

// K1: o1[b,o,l] = sum_i x[b,i,l]*w[i,o] + bias[o]. 4x4 micro-tiles, 64Lx64C.
__global__ void k_lin1(const float* __restrict__ x, const float* __restrict__ w,
                       const float* __restrict__ bias, float* __restrict__ o1) {
  __shared__ float xt[128][64];
  __shared__ float wt[128][64];
  int b = blockIdx.y, l0 = blockIdx.x * 64, cb = blockIdx.z * 64;
  int tid = threadIdx.x;
  int f4 = (tid & 15) * 4, r0 = tid >> 4;
#pragma unroll
  for (int s = 0; s < 8; ++s) {
    int r = r0 + s * 16;
    *(float4*)&xt[r][f4] = *(const float4*)&x[((long)b * 128 + r) * 4096 + l0 + f4];
    *(float4*)&wt[r][f4] = *(const float4*)&w[r * 128 + cb + f4];
  }
  __syncthreads();
  int tx = tid & 15, ty = tid >> 4;
  int c0 = tx * 4, t0 = ty * 4;
  float acc[4][4];
#pragma unroll
  for (int a = 0; a < 4; ++a) {
    float bv = bias[cb + t0 + a];
#pragma unroll
    for (int q = 0; q < 4; ++q) acc[a][q] = bv;
  }
  for (int k = 0; k < 128; ++k) {
    float4 xv = *(float4*)&xt[k][c0];
    float4 wv = *(float4*)&wt[k][t0];
    float xa[4] = {xv.x, xv.y, xv.z, xv.w};
    float wa[4] = {wv.x, wv.y, wv.z, wv.w};
#pragma unroll
    for (int a = 0; a < 4; ++a)
#pragma unroll
      for (int q = 0; q < 4; ++q) acc[a][q] += wa[a] * xa[q];
  }
#pragma unroll
  for (int a = 0; a < 4; ++a)
    *(float4*)&o1[((long)b * 128 + cb + t0 + a) * 4096 + l0 + c0] =
        make_float4(acc[a][0], acc[a][1], acc[a][2], acc[a][3]);
}

// K2: depthwise 3x3 SAME + bias + silu. 4x4 patch per thread from LDS plane.
__global__ void k_dw(const float* __restrict__ o1, const float* __restrict__ wgt,
                     const float* __restrict__ bias, float* __restrict__ o2) {
  __shared__ float p[4096];
  int bc = blockIdx.x, c = bc & 127, tid = threadIdx.x;
  const float* src = o1 + (long)bc * 4096;
#pragma unroll
  for (int s4 = 0; s4 < 4; ++s4) {
    int off = s4 * 1024 + tid * 4;
    *(float4*)&p[off] = *(const float4*)&src[off];
  }
  float wr[9];
#pragma unroll
  for (int j = 0; j < 9; ++j) wr[j] = wgt[c * 9 + j];
  float bv = bias[c];
  __syncthreads();
  int wg = tid & 15, hs = tid >> 4;
  int w0 = wg * 4, h0 = hs * 4;
  float in[6][6];
#pragma unroll
  for (int ri = 0; ri < 6; ++ri) {
    int h = h0 - 1 + ri;
    if (h < 0 || h > 63) {
#pragma unroll
      for (int ci = 0; ci < 6; ++ci) in[ri][ci] = 0.f;
    } else {
      float4 cc = *(float4*)&p[h * 64 + w0];
      in[ri][1] = cc.x; in[ri][2] = cc.y; in[ri][3] = cc.z; in[ri][4] = cc.w;
      in[ri][0] = (w0 > 0) ? p[h * 64 + w0 - 1] : 0.f;
      in[ri][5] = (w0 < 60) ? p[h * 64 + w0 + 4] : 0.f;
    }
  }
#pragma unroll
  for (int r = 0; r < 4; ++r) {
    float oc[4];
#pragma unroll
    for (int q = 0; q < 4; ++q) {
      float acc = bv;
#pragma unroll
      for (int dh = 0; dh < 3; ++dh)
#pragma unroll
        for (int dq = 0; dq < 3; ++dq)
          acc += in[r + dh][q + dq] * wr[dh * 3 + dq];
      oc[q] = siluf(acc);
    }
    *(float4*)&o2[(long)bc * 4096 + (h0 + r) * 64 + w0] =
        make_float4(oc[0], oc[1], oc[2], oc[3]);
  }
}

// K3: s[b,l,d] = sum_c o2[b,c,l]*w[c,d]  (d<32). 4x2 micro-tiles.
__global__ void k_fcin(const float* __restrict__ o2, const float* __restrict__ w,
                       float* __restrict__ s) {
  __shared__ float xt[128][64];
  __shared__ float wt[128][32];
  int b = blockIdx.y, l0 = blockIdx.x * 64;
  int tid = threadIdx.x;
  int f4 = (tid & 15) * 4, r0 = tid >> 4;
#pragma unroll
  for (int st = 0; st < 8; ++st) {
    int r = r0 + st * 16;
    *(float4*)&xt[r][f4] = *(const float4*)&o2[((long)b * 128 + r) * 4096 + l0 + f4];
  }
  int f4w = (tid & 7) * 4, rw = tid >> 3;
#pragma unroll
  for (int st = 0; st < 4; ++st) {
    int r = rw + st * 32;
    *(float4*)&wt[r][f4w] = *(const float4*)&w[r * 32 + f4w];
  }
  __syncthreads();
  int tx = tid & 15, ty = tid >> 4;
  int c0 = tx * 4, d0 = ty * 2;
  float acc[2][4] = {};
  for (int k = 0; k < 128; ++k) {
    float4 xv = *(float4*)&xt[k][c0];
    float2 wv = *(float2*)&wt[k][d0];
    float xa[4] = {xv.x, xv.y, xv.z, xv.w};
#pragma unroll
    for (int q = 0; q < 4; ++q) {
      acc[0][q] += wv.x * xa[q];
      acc[1][q] += wv.y * xa[q];
    }
  }
#pragma unroll
  for (int q = 0; q < 4; ++q) {
    long ob = ((long)b * 4096 + l0 + c0 + q) * 32 + d0;
    *(float2*)&s[ob] = make_float2(acc[0][q], acc[1][q]);
  }
}

// K4: in_proj + causal conv1d + silu + dt softplus + cum, both dirs, fused.
// Rolling-window conv in REGISTERS (round-6: 52KB xbcL LDS killed -> occupancy 2->8 blk/CU).
__global__ void k_inprojconv(const float* __restrict__ s, const float* __restrict__ Win,
                             const float* __restrict__ conv_w, const float* __restrict__ conv_b,
                             const float* __restrict__ dt_bias, const float* __restrict__ A_log,
                             float* __restrict__ z, float* __restrict__ xbca,
                             float* __restrict__ dts, float* __restrict__ cum) {
  __shared__ float st[67][36];      // s rows for seq idx l0-3..l0+63 (flip-resolved)
  int dir = blockIdx.z;
  int b = blockIdx.y, l0 = blockIdx.x * 64;
  int tid = threadIdx.x;
  for (int i = tid; i < 67 * 32; i += 256) {
    int rr = i >> 5, k2 = i & 31;
    int l = l0 - 3 + rr;
    float v = 0.f;
    if (l >= 0) {
      int lsrc = dir ? (4095 - l) : l;
      v = s[((long)b * 4096 + lsrc) * 32 + k2];
    }
    st[rr][k2] = v;
  }
  __syncthreads();
  const float* W = Win + (long)dir * 32 * 257;
  float wreg[32];
#pragma unroll
  for (int k2 = 0; k2 < 32; ++k2) wreg[k2] = W[k2 * 257 + tid];
  long rowbase = (long)b * 4096 + l0;
  if (tid < 64) {
    float* zp = z + (long)dir * ZSTRIDE;
    for (int r = 0; r < 64; ++r) {
      float a = 0.f;
#pragma unroll
      for (int k2 = 0; k2 < 32; k2 += 4) {
        float4 sv = *(float4*)&st[r + 3][k2];
        a += sv.x * wreg[k2] + sv.y * wreg[k2 + 1] + sv.z * wreg[k2 + 2] + sv.w * wreg[k2 + 3];
      }
      zp[(rowbase + r) * 64 + tid] = a;
    }
    // dt column (256) + softplus + wave prefix scan of log-decay
    float a = 0.f;
#pragma unroll
    for (int k2 = 0; k2 < 32; ++k2) a += st[tid + 3][k2] * W[k2 * 257 + 256];
    float v = a + dt_bias[dir];
    float sp = (v > 20.f) ? v : log1pf(expf(v));
    dts[dir * 32768 + rowbase + tid] = sp;
    float cd = -expf(A_log[dir]) * sp;
#pragma unroll
    for (int off = 1; off < 64; off <<= 1) {
      float u = __shfl_up(cd, off);
      if (tid >= off) cd += u;
    }
    cum[dir * 32768 + rowbase + tid] = cd;
  } else {
    int c = tid - 64;   // xbc channel 0..191
    float cw0 = conv_w[dir * 768 + c * 4 + 0];
    float cw1 = conv_w[dir * 768 + c * 4 + 1];
    float cw2 = conv_w[dir * 768 + c * 4 + 2];
    float cw3 = conv_w[dir * 768 + c * 4 + 3];
    float cb2 = conv_b[dir * 192 + c];
    float* xp = xbca + (long)dir * XSTRIDE;
    float win0 = 0.f, win1 = 0.f, win2 = 0.f, win3 = 0.f;
    for (int rr = 0; rr < 67; ++rr) {
      float a = 0.f;
#pragma unroll
      for (int k2 = 0; k2 < 32; k2 += 4) {
        float4 sv = *(float4*)&st[rr][k2];
        a += sv.x * wreg[k2] + sv.y * wreg[k2 + 1] + sv.z * wreg[k2 + 2] + sv.w * wreg[k2 + 3];
      }
      win0 = win1; win1 = win2; win2 = win3; win3 = a;
      if (rr >= 3) {
        float acc = cb2 + win0 * cw0 + win1 * cw1 + win2 * cw2 + win3 * cw3;
        xp[(rowbase + rr - 3) * 192 + c] = siluf(acc);
      }
    }
  }
}

// K6: chunk summary T[p][n] = sum_s f_s*X_s[p]*B_s[n].
__global__ void k_chunkT(const float* __restrict__ xbca, const float* __restrict__ dts,
                         const float* __restrict__ cum, float* __restrict__ T) {
  __shared__ float Xs[64][68], Bs[64][68];
  int dir = blockIdx.y;
  int bk = blockIdx.x, b = bk >> 6, k = bk & 63;
  int tid = threadIdx.x, lane = tid & 63, grp = tid >> 6;
  const float* xp = xbca + (long)dir * XSTRIDE;
  const float* dtp = dts + dir * 32768;
  const float* cp = cum + dir * 32768;
  long base = (long)b * 4096 + (long)k * 64;
  float clend = cp[base + 63];
  for (int r = grp; r < 64; r += 4) {
    float f = expf(clend - cp[base + r]) * dtp[base + r];
    Xs[r][lane] = xp[(base + r) * 192 + lane] * f;
    Bs[r][lane] = xp[(base + r) * 192 + 64 + lane];
  }
  __syncthreads();
  int tx = tid & 15, ty = tid >> 4;
  int p0 = ty * 4, n0 = tx * 4;
  float acc[4][4] = {};
  for (int s = 0; s < 64; ++s) {
    float4 xv = *(float4*)&Xs[s][p0];
    float4 bv = *(float4*)&Bs[s][n0];
    float xa[4] = {xv.x, xv.y, xv.z, xv.w};
    float ba[4] = {bv.x, bv.y, bv.z, bv.w};
#pragma unroll
    for (int a = 0; a < 4; ++a)
#pragma unroll
      for (int q = 0; q < 4; ++q) acc[a][q] += xa[a] * ba[q];
  }
#pragma unroll
  for (int a = 0; a < 4; ++a)
    *(float4*)&T[(long)dir * TSTRIDE + (long)bk * 4096 + (p0 + a) * 64 + n0] =
        make_float4(acc[a][0], acc[a][1], acc[a][2], acc[a][3]);
}

// K7: inter-chunk state scan (both dirs)
__global__ void k_scan(const float* __restrict__ T, const float* __restrict__ cum,
                       float* __restrict__ Sprev) {
  int idx = blockIdx.x * 256 + threadIdx.x;   // 65536
  int dir = idx >> 15, rem = idx & 32767;
  int b = rem >> 12, pn = rem & 4095;
  const float* Tp = T + (long)dir * TSTRIDE;
  float* Sp = Sprev + (long)dir * TSTRIDE;
  const float* cp = cum + dir * 32768 + b * 4096;
  float sacc = 0.f;
  for (int k = 0; k < 64; ++k) {
    long o = ((long)(b * 64 + k)) * 4096 + pn;
    Sp[o] = sacc;
    sacc = expf(cp[k * 64 + 63]) * sacc + Tp[o];
  }
}

// K8: per-chunk Y + gate + RMSNorm + out-proj, fully fused.
__global__ void k_chunkYout(const float* __restrict__ xbca, const float* __restrict__ dts,
                            const float* __restrict__ cum, const float* __restrict__ Sprev,
                            const float* __restrict__ Dp, const float* __restrict__ z,
                            const float* __restrict__ normw, const float* __restrict__ Wout,
                            float* __restrict__ s2a, float* __restrict__ s2b) {
  __shared__ float U[64][65];
  __shared__ float V[64][65];
  __shared__ float G[64][65];
  __shared__ float cumS[64];
  __shared__ float part[4][64];
  __shared__ float rsc[64];
  int dir = blockIdx.y;
  int bk = blockIdx.x, b = bk >> 6, k = bk & 63;
  int tid = threadIdx.x, lane = tid & 63, grp = tid >> 6;
  const float* xp = xbca + (long)dir * XSTRIDE;
  const float* dtp = dts + dir * 32768;
  const float* cp = cum + dir * 32768;
  const float* Sp = Sprev + (long)dir * TSTRIDE;
  const float* zp = z + (long)dir * ZSTRIDE;
  long base = (long)b * 4096 + (long)k * 64;
  for (int r = grp; r < 64; r += 4) {
    float dtv = dtp[base + r];
    U[r][lane] = xp[(base + r) * 192 + 64 + lane] * dtv;
    V[r][lane] = xp[(base + r) * 192 + 128 + lane];
  }
  if (tid < 64) cumS[tid] = cp[base + tid];
  __syncthreads();
  int tx = tid & 15, ty = tid >> 4;
  int t0 = ty * 4, c0 = tx * 4;
  {
    float g[4][4] = {};
    for (int i = 0; i < 64; ++i) {
      float cv[4], uv[4];
#pragma unroll
      for (int a = 0; a < 4; ++a) cv[a] = V[t0 + a][i];
#pragma unroll
      for (int a = 0; a < 4; ++a) uv[a] = U[c0 + a][i];
#pragma unroll
      for (int a = 0; a < 4; ++a)
#pragma unroll
        for (int bb = 0; bb < 4; ++bb) g[a][bb] += cv[a] * uv[bb];
    }
#pragma unroll
    for (int a = 0; a < 4; ++a) {
      float ct = cumS[t0 + a];
#pragma unroll
      for (int bb = 0; bb < 4; ++bb) {
        int l = c0 + bb;
        G[t0 + a][l] = (l <= t0 + a) ? g[a][bb] * expf(ct - cumS[l]) : 0.f;
      }
    }
  }
  __syncthreads();
  for (int r = grp; r < 64; r += 4)
    U[r][lane] = Sp[(long)bk * 4096 + r * 64 + lane];
  __syncthreads();
  float inter[4][4] = {};
  for (int n = 0; n < 64; ++n) {
    float cv[4], sv[4];
#pragma unroll
    for (int a = 0; a < 4; ++a) cv[a] = V[t0 + a][n];
#pragma unroll
    for (int a = 0; a < 4; ++a) sv[a] = U[c0 + a][n];
#pragma unroll
    for (int a = 0; a < 4; ++a)
#pragma unroll
      for (int bb = 0; bb < 4; ++bb) inter[a][bb] += cv[a] * sv[bb];
  }
  __syncthreads();
  for (int r = grp; r < 64; r += 4)
    V[r][lane] = xp[(base + r) * 192 + lane];
  __syncthreads();
  float Dv = Dp[dir];
  float acc[4][4];
#pragma unroll
  for (int a = 0; a < 4; ++a) {
    float et = expf(cumS[t0 + a]);
#pragma unroll
    for (int bb = 0; bb < 4; ++bb)
      acc[a][bb] = et * inter[a][bb] + Dv * V[t0 + a][c0 + bb];
  }
  for (int s = 0; s < 64; ++s) {
    float gv[4], xv[4];
#pragma unroll
    for (int a = 0; a < 4; ++a) gv[a] = G[t0 + a][s];
#pragma unroll
    for (int a = 0; a < 4; ++a) xv[a] = V[s][c0 + a];
#pragma unroll
    for (int a = 0; a < 4; ++a)
#pragma unroll
      for (int bb = 0; bb < 4; ++bb) acc[a][bb] += gv[a] * xv[bb];
  }
  __syncthreads();
#pragma unroll
  for (int a = 0; a < 4; ++a) {
    float4 zv = *(const float4*)&zp[(base + t0 + a) * 64 + c0];
    G[t0 + a][c0 + 0] = acc[a][0] * siluf(zv.x);
    G[t0 + a][c0 + 1] = acc[a][1] * siluf(zv.y);
    G[t0 + a][c0 + 2] = acc[a][2] * siluf(zv.z);
    G[t0 + a][c0 + 3] = acc[a][3] * siluf(zv.w);
  }
  for (int i = tid; i < 2048; i += 256) {
    int p = i >> 5, d = i & 31;
    V[p][d] = normw[dir * 64 + p] * Wout[(long)dir * 2048 + p * 32 + d];
  }
  __syncthreads();
  {
    int wv = tid >> 6, rw = tid & 63;
    float pp = 0.f;
    for (int p2 = wv * 16; p2 < wv * 16 + 16; ++p2) { float v = G[rw][p2]; pp += v * v; }
    part[wv][rw] = pp;
  }
  __syncthreads();
  if (tid < 64)
    rsc[tid] = rsqrtf((part[0][tid] + part[1][tid] + part[2][tid] + part[3][tid]) *
                          (1.0f / 64.0f) + 1e-5f);
  __syncthreads();
  int tx2 = tid & 31, ty2 = tid >> 5;
  float a8[8] = {};
  for (int p = 0; p < 64; ++p) {
    float wv = V[p][tx2];
#pragma unroll
    for (int r8 = 0; r8 < 8; ++r8) a8[r8] += G[ty2 * 8 + r8][p] * wv;
  }
  float* s2x = dir ? s2b : s2a;
#pragma unroll
  for (int r8 = 0; r8 < 8; ++r8) {
    int r = ty2 * 8 + r8;
    int l = k * 64 + r;
    int lout = dir ? (4095 - l) : l;
    s2x[((long)b * 4096 + lout) * 32 + tx2] = a8[r8] * rsc[r];
  }
}

// K10: o3 = (s2a+s2b)@W — pure GEMM.
__global__ void k_fcout(const float* __restrict__ s2a, const float* __restrict__ s2b,
                        const float* __restrict__ w, float* __restrict__ o3) {
  __shared__ float st[32][68];
  __shared__ float wt[32][64];
  int b = blockIdx.y, l0 = blockIdx.x * 64, cb = blockIdx.z * 64;
  int tid = threadIdx.x;
  {
    int d = tid & 31, l = tid >> 5;
    for (int si = 0; si < 8; ++si) {
      int ll = l + si * 8;
      long o = ((long)b * 4096 + l0 + ll) * 32 + d;
      st[d][ll] = s2a[o] + s2b[o];
    }
    int f4 = (tid & 15) * 4, r = tid >> 4;
    for (int si = 0; si < 2; ++si) {
      int rr = r + si * 16;
      *(float4*)&wt[rr][f4] = *(const float4*)&w[rr * 128 + cb + f4];
    }
  }
  __syncthreads();
  int tx = tid & 15, ty = tid >> 4;
  int c0 = tx * 4, t0 = ty * 4;
  float acc[4][4] = {};
  for (int k = 0; k < 32; ++k) {
    float4 xv = *(float4*)&st[k][c0];
    float4 wv = *(float4*)&wt[k][t0];
    float xa[4] = {xv.x, xv.y, xv.z, xv.w};
    float wa[4] = {wv.x, wv.y, wv.z, wv.w};
#pragma unroll
    for (int a = 0; a < 4; ++a)
#pragma unroll
      for (int q = 0; q < 4; ++q) acc[a][q] += wa[a] * xa[q];
  }
#pragma unroll
  for (int a = 0; a < 4; ++a)
    *(float4*)&o3[((long)b * 128 + cb + t0 + a) * 4096 + l0 + c0] =
        make_float4(acc[a][0], acc[a][1], acc[a][2], acc[a][3]);
}

// K10b: per-channel sums for BatchNorm (2 atomics per block)
__global__ void k_bnstat(const float* __restrict__ o3, float* __restrict__ stats) {
  int bc = blockIdx.x;  // 1024 = (b,c)
  int tid = threadIdx.x;
  const float* p = o3 + (long)bc * 4096;
  float s = 0.f, q = 0.f;
  for (int i = tid * 4; i < 4096; i += 1024) {
    float4 v = *(const float4*)&p[i];
    s += v.x + v.y + v.z + v.w;
    q += v.x * v.x + v.y * v.y + v.z * v.z + v.w * v.w;
  }
  __shared__ float rs[4], rq[4];
  for (int off = 32; off; off >>= 1) { s += __shfl_down(s, off); q += __shfl_down(q, off); }
  if ((tid & 63) == 0) { rs[tid >> 6] = s; rq[tid >> 6] = q; }
  __syncthreads();
  if (tid == 0) {
    float a = rs[0] + rs[1] + rs[2] + rs[3];
    float b2 = rq[0] + rq[1] + rq[2] + rq[3];
    int c = bc & 127;
    atomicAdd(&stats[c], a);
    atomicAdd(&stats[128 + c], b2);
  }
}

// K12: BN + conv4 (128->128) + sigmoid + gated residual. 4x4 micro-tiles.
__global__ void k_final(const float* __restrict__ o3, const float* __restrict__ stats,
                        const float* __restrict__ bng, const float* __restrict__ bnb,
                        const float* __restrict__ w, const float* __restrict__ bias,
                        const float* __restrict__ x, float* __restrict__ out) {
  __shared__ float xt[128][64];
  __shared__ float wt[128][64];
  __shared__ float sc[128], sh[128];
  int b = blockIdx.y, l0 = blockIdx.x * 64, cb = blockIdx.z * 64;
  int tid = threadIdx.x;
  if (tid < 128) {
    float mu = stats[tid] * (1.0f / 32768.0f);
    float var = stats[128 + tid] * (1.0f / 32768.0f) - mu * mu;
    float r = rsqrtf(var + 1e-5f);
    sc[tid] = r * bng[tid];
    sh[tid] = bnb[tid] - mu * r * bng[tid];
  }
  __syncthreads();
  int f4 = (tid & 15) * 4, r0 = tid >> 4;
#pragma unroll
  for (int s = 0; s < 8; ++s) {
    int r = r0 + s * 16;
    float4 v = *(const float4*)&o3[((long)b * 128 + r) * 4096 + l0 + f4];
    float scr = sc[r], shr = sh[r];
    *(float4*)&xt[r][f4] = make_float4(fmaf(v.x, scr, shr), fmaf(v.y, scr, shr),
                                       fmaf(v.z, scr, shr), fmaf(v.w, scr, shr));
    *(float4*)&wt[r][f4] = *(const float4*)&w[r * 128 + cb + f4];
  }
  __syncthreads();
  int tx = tid & 15, ty = tid >> 4;
  int c0 = tx * 4, t0 = ty * 4;
  float acc[4][4];
#pragma unroll
  for (int a = 0; a < 4; ++a) {
    float bv = bias[cb + t0 + a];
#pragma unroll
    for (int q = 0; q < 4; ++q) acc[a][q] = bv;
  }
  for (int k = 0; k < 128; ++k) {
    float4 xv = *(float4*)&xt[k][c0];
    float4 wv = *(float4*)&wt[k][t0];
    float xa[4] = {xv.x, xv.y, xv.z, xv.w};
    float wa[4] = {wv.x, wv.y, wv.z, wv.w};
#pragma unroll
    for (int a = 0; a < 4; ++a)
#pragma unroll
      for (int q = 0; q < 4; ++q) acc[a][q] += wa[a] * xa[q];
  }
#pragma unroll
  for (int a = 0; a < 4; ++a) {
    long xi = ((long)b * 128 + cb + t0 + a) * 4096 + l0 + c0;
    float4 xv = *(const float4*)&x[xi];
    float4 o4;
    o4.x = xv.x * (1.0f + 1.0f / (1.0f + expf(-acc[a][0])));
    o4.y = xv.y * (1.0f + 1.0f / (1.0f + expf(-acc[a][1])));
    o4.z = xv.z * (1.0f + 1.0f / (1.0f + expf(-acc[a][2])));
    o4.w = xv.w * (1.0f + 1.0f / (1.0f + expf(-acc[a][3])));
    *(float4*)&out[xi] = o4;
  }
}

extern "C" void kernel_launch(void* const* d_in, const int* in_sizes, int n_in,
                              void* d_out, int out_size, void* d_ws, size_t ws_size,
                              hipStream_t stream) {
  const float* x          = (const float*)d_in[0];
  const float* lin1_w     = (const float*)d_in[1];
  const float* lin1_b     = (const float*)d_in[2];
  const float* dw_w       = (const float*)d_in[3];
  const float* dw_b       = (const float*)d_in[4];
  const float* fc_in_w    = (const float*)d_in[5];
  const float* mam_in_w   = (const float*)d_in[6];
  const float* mam_conv_w = (const float*)d_in[7];
  const float* mam_conv_b = (const float*)d_in[8];
  const float* mam_dt_bias= (const float*)d_in[9];
  const float* mam_A_log  = (const float*)d_in[10];
  const float* mam_D      = (const float*)d_in[11];
  const float* mam_norm_w = (const float*)d_in[12];
  const float* mam_out_w  = (const float*)d_in[13];
  const float* fc_out_w   = (const float*)d_in[14];
  const float* bn_g       = (const float*)d_in[15];
  const float* bn_b       = (const float*)d_in[16];
  const float* conv4_w    = (const float*)d_in[17];
  const float* conv4_b    = (const float*)d_in[18];
  float* out = (float*)d_out;
  float* ws  = (float*)d_ws;

  float* o1   = ws + OFF_O1;
  float* o2   = ws + OFF_O2;
  float* sbuf = ws + OFF_S;
  float* zbuf = ws + OFF_Z;
  float* xbca = ws + OFF_XBCA;
  float* dts  = ws + OFF_DTS;
  float* cum  = ws + OFF_CUM;
  float* Tbuf = ws + OFF_T;
  float* Sprev= ws + OFF_SPREV;
  float* s2a  = ws + OFF_S2A;
  float* s2b  = ws + OFF_S2B;
  float* bnst = ws + OFF_BN;
  float* o3   = ws + OFF_O3;

  hipMemsetAsync(bnst, 0, 256 * sizeof(float), stream);

  k_lin1<<<dim3(64, 8, 2), 256, 0, stream>>>(x, lin1_w, lin1_b, o1);
  k_dw<<<1024, 256, 0, stream>>>(o1, dw_w, dw_b, o2);
  k_fcin<<<dim3(64, 8), 256, 0, stream>>>(o2, fc_in_w, sbuf);
  k_inprojconv<<<dim3(64, 8, 2), 256, 0, stream>>>(sbuf, mam_in_w, mam_conv_w, mam_conv_b,
                                                   mam_dt_bias, mam_A_log,
                                                   zbuf, xbca, dts, cum);
  k_chunkT<<<dim3(512, 2), 256, 0, stream>>>(xbca, dts, cum, Tbuf);
  k_scan<<<256, 256, 0, stream>>>(Tbuf, cum, Sprev);
  k_chunkYout<<<dim3(512, 2), 256, 0, stream>>>(xbca, dts, cum, Sprev, mam_D, zbuf,
                                                mam_norm_w, mam_out_w, s2a, s2b);
  k_fcout<<<dim3(64, 8, 2), 256, 0, stream>>>(s2a, s2b, fc_out_w, o3);
  k_bnstat<<<1024, 256, 0, stream>>>(o3, bnst);
  k_final<<<dim3(64, 8, 2), 256, 0, stream>>>(o3, bnst, bn_g, bn_b, conv4_w, conv4_b, x, out);
}